// Round 6
// baseline (551.907 us; speedup 1.0000x reference)
//
#include <hip/hip_runtime.h>
#include <hip/hip_bf16.h>

#define N_NODES   100000
#define N_EDGES   1600000
#define F_IN      64
#define HID       64
#define N_CLASSES 45
#define N_GRAPHS  256
#define SB        392         // super-buckets: bucket = dst >> 8 (array sizing)
#define NB        391         // buckets that can contain nodes/edges
#define NPB       256         // nodes per bucket
#define CAP       4608        // fixed bucket capacity (mean 4082, sigma 64 -> +8s)
#define CHUNK     4096        // edges per scatter workgroup
#define NCHUNK    391         // ceil(N_EDGES / CHUNK)
#define GEMM_GRID 3125        // N_NODES/32
#define AGG_GRID  6256        // NB*64 quads / 4 waves per block

__device__ __forceinline__ float rl_f(float v, int k) {
    return __uint_as_float(__builtin_amdgcn_readlane(__float_as_uint(v), k));
}
__device__ __forceinline__ int rl_i(int v, int k) {
    return __builtin_amdgcn_readlane(v, k);
}
// fp32 <-> bf16 (RNE)
__device__ __forceinline__ unsigned short f2bf(float x) {
    unsigned u = __float_as_uint(x);
    unsigned r = u + 0x7FFFu + ((u >> 16) & 1u);
    return (unsigned short)(r >> 16);
}
__device__ __forceinline__ float bf2f(unsigned short h) {
    return __uint_as_float(((unsigned)h) << 16);
}

// ---------------- front kernel: scatter | gemm1 ----------------
// payload: src(17b) | dstLow(8b)<<17
__global__ __launch_bounds__(256) void k_front(const int* __restrict__ src, const int* __restrict__ dst,
                                               int* __restrict__ bcur, int* __restrict__ binned,
                                               const float* __restrict__ x, const float* __restrict__ W1,
                                               unsigned short* __restrict__ P) {
    int bid = blockIdx.x;
    int t   = threadIdx.x;
    if (bid < NCHUNK) {
        // ---- scatter (bucket multisplit) ----
        __shared__ int stg[CHUNK];
        __shared__ unsigned short bkt[CHUNK];
        __shared__ int h[512], cur[512], off[512];
        __shared__ int ps[256];
        h[t] = 0; h[t + 256] = 0;
        __syncthreads();
        int base4 = bid * (CHUNK / 4);
        // phase 1: histogram (dst read #1)
        #pragma unroll
        for (int i = 0; i < CHUNK / 1024; i++) {
            int e4 = base4 + i * 256 + t;
            if (e4 < N_EDGES / 4) {
                int4 d = ((const int4*)dst)[e4];
                atomicAdd(&h[d.x >> 8], 1);
                atomicAdd(&h[d.y >> 8], 1);
                atomicAdd(&h[d.z >> 8], 1);
                atomicAdd(&h[d.w >> 8], 1);
            }
        }
        __syncthreads();
        // phase 2: pair-scan over 512 slots + global reservation; off = gbase - lbase
        int a0 = h[2 * t], a1 = h[2 * t + 1];
        ps[t] = a0 + a1;
        __syncthreads();
        for (int o = 1; o < 256; o <<= 1) {
            int v = (t >= o) ? ps[t - o] : 0;
            __syncthreads();
            if (t >= o) ps[t] += v;
            __syncthreads();
        }
        int pex = ps[t] - (a0 + a1);               // exclusive over pairs
        int e0 = pex, e1 = pex + a0;
        cur[2 * t] = e0; cur[2 * t + 1] = e1;
        if (2 * t < SB && a0 > 0)
            off[2 * t] = (2 * t) * CAP + atomicAdd(&bcur[2 * t], a0) - e0;
        if (2 * t + 1 < SB && a1 > 0)
            off[2 * t + 1] = (2 * t + 1) * CAP + atomicAdd(&bcur[2 * t + 1], a1) - e1;
        __syncthreads();
        int total = ps[255];                        // edges in this chunk
        // phase 3: re-read dst (+src), stage payload + bucket id
        #pragma unroll
        for (int i = 0; i < CHUNK / 1024; i++) {
            int e4 = base4 + i * 256 + t;
            if (e4 < N_EDGES / 4) {
                int4 d  = ((const int4*)dst)[e4];   // L2-hot re-read
                int4 s4 = ((const int4*)src)[e4];
                int q;
                q = atomicAdd(&cur[d.x >> 8], 1); stg[q] = s4.x | ((d.x & 255) << 17); bkt[q] = (unsigned short)(d.x >> 8);
                q = atomicAdd(&cur[d.y >> 8], 1); stg[q] = s4.y | ((d.y & 255) << 17); bkt[q] = (unsigned short)(d.y >> 8);
                q = atomicAdd(&cur[d.z >> 8], 1); stg[q] = s4.z | ((d.z & 255) << 17); bkt[q] = (unsigned short)(d.z >> 8);
                q = atomicAdd(&cur[d.w >> 8], 1); stg[q] = s4.w | ((d.w & 255) << 17); bkt[q] = (unsigned short)(d.w >> 8);
            }
        }
        __syncthreads();
        // phase 4: flat flush — coalesced LDS read, run-coalesced global write
        for (int i = t; i < total; i += 256) {
            int b = bkt[i];
            binned[off[b] + i] = stg[i];
        }
    } else {
        // ---- gemm1: H1 = x @ W1 (bf16) ----
        int gbid = bid - NCHUNK;
        int lane = t & 63;
        int wv   = t >> 6;
        int base = gbid * 32 + wv * 8;
        float xr[8], acc[8];
        #pragma unroll
        for (int r = 0; r < 8; r++) {
            xr[r]  = x[(size_t)(base + r) * 64 + lane];
            acc[r] = 0.f;
        }
        for (int kb = 0; kb < 64; kb += 8) {
            float wb[8];
            #pragma unroll
            for (int j = 0; j < 8; j++) wb[j] = W1[(kb + j) * 64 + lane];
            #pragma unroll
            for (int j = 0; j < 8; j++) {
                #pragma unroll
                for (int r = 0; r < 8; r++)
                    acc[r] = fmaf(rl_f(xr[r], kb + j), wb[j], acc[r]);
            }
        }
        #pragma unroll
        for (int r = 0; r < 8; r++)
            P[(size_t)(base + r) * 64 + lane] = f2bf(acc[r]);
    }
}

// ---------------- per-bucket: degrees -> dinv/dinv2 + node-sorted csr + degree-sorted quads ----------------
// ndesc[b*256 + pos] (pos = degree-sorted rank in bucket) =
//     (csr_start - b*CAP) (13b) | nodeLow (8b) << 13 | deg (11b, clamped 2047) << 21
// Sorting by degree makes each quad (4 consecutive sorted nodes) degree-homogeneous, so
// a wave processing 4 nodes in lockstep wastes ~nothing on the max-degree loop bound.
// Deg-0 nodes (and the tail slots n >= N_NODES) sort first, forming near-free quads.
__global__ __launch_bounds__(256) void k_bcsr(const int* __restrict__ binned, const int* __restrict__ bcur,
                                              float* __restrict__ dinv, float* __restrict__ dinv2,
                                              int* __restrict__ csr, unsigned* __restrict__ ndesc) {
    __shared__ int h[NPB];
    __shared__ int ts[NPB];
    __shared__ int dh[128];
    __shared__ int doff[128];
    int t = threadIdx.x;
    int b = blockIdx.x;
    int nb0  = b << 8;
    int ebeg = b * CAP;
    int ecnt = bcur[b]; if (ecnt > CAP) ecnt = CAP;
    h[t] = 0;
    if (t < 128) dh[t] = 0;
    __syncthreads();
    for (int i = t; i < ecnt; i += 256)
        atomicAdd(&h[binned[ebeg + i] >> 17], 1);
    __syncthreads();
    int c = h[t];
    ts[t] = c;
    __syncthreads();
    for (int o = 1; o < 256; o <<= 1) {
        int v = (t >= o) ? ts[t - o] : 0;
        __syncthreads();
        if (t >= o) ts[t] += v;
        __syncthreads();
    }
    int excl = ts[t] - c + ebeg;                   // global csr start for node (b<<8)+t
    int n = nb0 + t;
    if (n < N_NODES) {
        float inv = 1.0f / (float)(c + 1);         // +1 self loop
        dinv2[n] = inv;
        dinv[n]  = sqrtf(inv);
    }
    // ---- counting sort by degree -> quad descriptors ----
    int bin = c < 127 ? c : 127;
    atomicAdd(&dh[bin], 1);
    __syncthreads();
    if (t == 0) {
        int s = 0;
        #pragma unroll 4
        for (int i = 0; i < 128; i++) { int v = dh[i]; doff[i] = s; s += v; }
    }
    __syncthreads();
    int pos = atomicAdd(&doff[bin], 1);
    int cc  = c < 2047 ? c : 2047;
    ndesc[nb0 + pos] = (unsigned)(excl - ebeg) | ((unsigned)t << 13) | ((unsigned)cc << 21);
    __syncthreads();
    h[t] = excl;                                   // per-node write cursor
    __syncthreads();
    for (int i = t; i < ecnt; i += 256) {
        int p = binned[ebeg + i];
        int q = atomicAdd(&h[p >> 17], 1);
        csr[q] = p;                                // keep src | dstLow<<17
    }
}

// ---------------- GEMM layers 2/3 ----------------
// xin = relu(E[n] + bprev + Hprev[n]*dinv2[n]);  Hnew = xin @ W  (bf16, in-place in P)
// POOLI (layer 3): pool[batch[n]] += bcurr + Hnew[n]*dinv2[n]
template<bool POOLI>
__global__ __launch_bounds__(256) void k_gemm(const float* __restrict__ E,
                                              unsigned short* P,            // aliased in/out (row-private)
                                              const float* __restrict__ W,
                                              const float* __restrict__ bprev,
                                              const float* __restrict__ bcurr,
                                              const float* __restrict__ dinv2,
                                              const int* __restrict__ batch,
                                              float* __restrict__ pool) {
    int lane = threadIdx.x & 63;
    int wv   = threadIdx.x >> 6;
    int base = blockIdx.x * 32 + wv * 8;           // grid exact (3125*32)
    float bp = bprev[lane];
    float xr[8], acc[8];
    #pragma unroll
    for (int r = 0; r < 8; r++) {
        int n = base + r;
        float hp = bf2f(P[(size_t)n * 64 + lane]);
        float a  = E[(size_t)n * 64 + lane] + fmaf(hp, dinv2[n], bp);
        xr[r]  = fmaxf(a, 0.f);
        acc[r] = 0.f;
    }
    for (int kb = 0; kb < 64; kb += 8) {
        float wb[8];
        #pragma unroll
        for (int j = 0; j < 8; j++) wb[j] = W[(kb + j) * 64 + lane];
        #pragma unroll
        for (int j = 0; j < 8; j++) {
            #pragma unroll
            for (int r = 0; r < 8; r++)
                acc[r] = fmaf(rl_f(xr[r], kb + j), wb[j], acc[r]);
        }
    }
    #pragma unroll
    for (int r = 0; r < 8; r++)
        P[(size_t)(base + r) * 64 + lane] = f2bf(acc[r]);
    if (POOLI) {
        float bv = bcurr[lane];
        float d2[8];
        #pragma unroll
        for (int r = 0; r < 8; r++) d2[r] = dinv2[base + r];
        int g0 = batch[base], g7 = batch[base + 7];
        if (g0 == g7) {
            float s = 0.f;
            #pragma unroll
            for (int r = 0; r < 8; r++) s += fmaf(acc[r], d2[r], bv);
            atomicAdd(&pool[g0 * 64 + lane], s);
        } else {
            #pragma unroll
            for (int r = 0; r < 8; r++) {
                int g = batch[base + r];
                atomicAdd(&pool[g * 64 + lane], fmaf(acc[r], d2[r], bv));
            }
        }
    }
}

// ---------------- Quad-node aggregation: 4 edges per gather instruction ----------------
// One wave owns 4 degree-matched nodes (one per 16-lane group qw; ql = feature quad).
// Per step, lane (qw,ql) processes edge k of node qw, features 4ql..4ql+3 via a uint2
// (8B) slice -> each gather instruction covers 4 full 128B H rows (512B, 4x the MLP of
// the 2B/lane form) and per-edge VALU drops ~15 -> ~3.5 (no run detection: runs are
// lane-group-aligned by construction; degree masking folded into the preloaded coef,
// one cndmask per 16 edges). Edge metadata reaches lanes via 2 ds_bpermute per step
// (lgkm pipe). Flush: ONE plain global_store_dwordx4 covering all 4 node rows
// (exclusive ownership, no atomics, no pre-zero; deg-0 rows store zeros).
// POOLEP (layer 3): 4 atomic insts = 1 per node into pool[batch[n]].
template<bool POOLEP>
__global__ __launch_bounds__(256, 6) void k_agge(const unsigned short* __restrict__ Hbuf,
                                                 const int* __restrict__ csr,
                                                 const unsigned* __restrict__ ndesc,
                                                 const float* __restrict__ dinv,
                                                 const int* __restrict__ batch,
                                                 float* __restrict__ Out) {
    int t    = threadIdx.x;
    int wv   = t >> 6;
    int lane = t & 63;
    int ql   = lane & 15;
    int wid  = blockIdx.x * 4 + wv;                // 0 .. NB*64-1
    int b    = wid >> 6;                           // bucket
    int q    = wid & 63;                           // quad within bucket
    unsigned dsc = ndesc[(b << 8) + q * 4 + (lane >> 4)];
    int start = b * CAP + (int)(dsc & 0x1FFFu);    // csr start of my qw's node
    int deg   = (int)(dsc >> 21);
    int n     = (b << 8) + (int)((dsc >> 13) & 0xFFu);
    int dmax  = max(max(rl_i(deg, 0), rl_i(deg, 16)), max(rl_i(deg, 32), rl_i(deg, 48)));
    int bpb   = (lane & 48) << 2;                  // bpermute base byte (= qw*16 lanes * 4)

    float a0 = 0.f, a1 = 0.f, a2 = 0.f, a3 = 0.f;
    for (int kb = 0; kb < dmax; kb += 16) {
        // preload 16 csr slots per node group; coef pre-masked past degree
        int   sl   = start + kb + ql;
        int   pl   = csr[sl];
        float craw = dinv[pl & 0x1FFFF];
        float cl   = (kb + ql < deg) ? craw : 0.f;
        int   cli  = __float_as_int(cl);
        #pragma unroll
        for (int hh = 0; hh < 2; hh++) {
            if (hh == 1 && kb + 8 >= dmax) break;  // uniform
            int pm[8], cm[8];
            #pragma unroll
            for (int j = 0; j < 8; j++) {          // 16 ds ops, lgkm pipe
                int ai = bpb + ((hh << 3) + j) << 2;
                pm[j] = __builtin_amdgcn_ds_bpermute((bpb + ((hh << 3) + j) * 4), pl);
                cm[j] = __builtin_amdgcn_ds_bpermute((bpb + ((hh << 3) + j) * 4), cli);
                (void)ai;
            }
            uint2 u[8];
            #pragma unroll
            for (int j = 0; j < 8; j++) {          // 8 x 512B gathers in flight
                unsigned voff = ((unsigned)(pm[j] & 0x1FFFF) << 7) + (unsigned)(ql << 3);
                u[j] = *(const uint2*)((const char*)Hbuf + voff);
            }
            #pragma unroll
            for (int j = 0; j < 8; j++) {
                float c = __int_as_float(cm[j]);   // 0 past degree -> garbage rows ignored
                a0 = fmaf(__uint_as_float(u[j].x << 16),          c, a0);
                a1 = fmaf(__uint_as_float(u[j].x & 0xFFFF0000u),  c, a1);
                a2 = fmaf(__uint_as_float(u[j].y << 16),          c, a2);
                a3 = fmaf(__uint_as_float(u[j].y & 0xFFFF0000u),  c, a3);
            }
        }
    }
    bool valid = (n < N_NODES);
    float dn = dinv[valid ? n : 0];
    a0 *= dn; a1 *= dn; a2 *= dn; a3 *= dn;
    if (!POOLEP) {
        if (valid) {                               // one dwordx4: 4 complete 256B rows/wave
            float4 v = make_float4(a0, a1, a2, a3);
            *(float4*)(Out + (size_t)n * 64 + ql * 4) = v;
        }
    } else {
        if (valid && deg > 0) {
            int g = batch[n];                      // uniform within 16-lane group
            float* o = Out + (size_t)g * 64 + ql * 4;
            atomicAdd(o + 0, a0);
            atomicAdd(o + 1, a1);
            atomicAdd(o + 2, a2);
            atomicAdd(o + 3, a3);
        }
    }
}

// ---------------- mean + classifier ----------------
__device__ __forceinline__ int lbound(const int* __restrict__ a, int n, int v) {
    int lo = 0, hi = n;
    while (lo < hi) { int m = (lo + hi) >> 1; if (a[m] < v) lo = m + 1; else hi = m; }
    return lo;
}

__global__ __launch_bounds__(64) void k_cls(const float* __restrict__ pool, const int* __restrict__ batch,
                                            const float* __restrict__ Wl, const float* __restrict__ bl,
                                            float* __restrict__ out) {
    __shared__ float pm[64];
    __shared__ int bounds[2];
    int g = blockIdx.x;
    int t = threadIdx.x;
    if (t < 2) bounds[t] = lbound(batch, N_NODES, g + t);
    __syncthreads();
    float cnt = (float)(bounds[1] - bounds[0]);
    pm[t] = pool[g * 64 + t] / fmaxf(cnt, 1.0f);
    __syncthreads();
    if (t < N_CLASSES) {
        float o = bl[t];
        #pragma unroll
        for (int k = 0; k < HID; k++) o = fmaf(pm[k], Wl[k * N_CLASSES + t], o);
        out[g * N_CLASSES + t] = o;
    }
}

// ---------------- launch ----------------

extern "C" void kernel_launch(void* const* d_in, const int* in_sizes, int n_in,
                              void* d_out, int out_size, void* d_ws, size_t ws_size,
                              hipStream_t stream) {
    const float* x     = (const float*)d_in[0];
    const int*   eidx  = (const int*)  d_in[1];
    const int*   batch = (const int*)  d_in[2];
    const float* W1 = (const float*)d_in[3];
    const float* b1 = (const float*)d_in[4];
    const float* W2 = (const float*)d_in[5];
    const float* b2 = (const float*)d_in[6];
    const float* W3 = (const float*)d_in[7];
    const float* b3 = (const float*)d_in[8];
    const float* Wl = (const float*)d_in[9];
    const float* bl = (const float*)d_in[10];
    const int* src = eidx;
    const int* dst = eidx + N_EDGES;

    char* p = (char*)d_ws;
    auto alloc = [&](size_t bytes) -> void* {
        void* r = (void*)p;
        p += (bytes + 255) & ~(size_t)255;
        return r;
    };
    float* dinv  = (float*)alloc((size_t)N_NODES * 4);
    float* dinv2 = (float*)alloc((size_t)N_NODES * 4);
    int*   csr   = (int*)  alloc((size_t)SB * CAP * 4);
    unsigned short* P = (unsigned short*)alloc((size_t)N_NODES * 64 * 2);  // bf16 H
    float* E1    = (float*)alloc((size_t)N_NODES * 64 * 4);   // edge sums L1 (no pre-zero)
    float* pool  = (float*)alloc((size_t)N_GRAPHS * 64 * 4);
    float* E2    = (float*)alloc((size_t)N_NODES * 64 * 4);   // edge sums L2 (no pre-zero)
    int*   bcur  = (int*)  alloc((size_t)SB * 4);
    int*   binned = (int*) alloc((size_t)SB * CAP * 4);
    unsigned* ndesc = (unsigned*)alloc((size_t)NB * NPB * 4); // degree-sorted node descriptors

    // ---- front: scatter | gemm1 (independent roles) ----
    hipMemsetAsync(bcur, 0, (size_t)SB * 4, stream);
    hipMemsetAsync(pool, 0, (size_t)N_GRAPHS * 64 * 4, stream);
    k_front<<<NCHUNK + GEMM_GRID, 256, 0, stream>>>(src, dst, bcur, binned, x, W1, P);
    k_bcsr <<<NB, 256, 0, stream>>>(binned, bcur, dinv, dinv2, csr, ndesc);

    // layer 1 edges: H1 gathers -> E1 (exclusive plain stores)
    k_agge<false><<<AGG_GRID, 256, 0, stream>>>(P, csr, ndesc, dinv, batch, E1);
    // layer 2: relu(E1 + b1 + H1*dinv2) @ W2 -> H2 (in-place in P); edges -> E2
    k_gemm<false><<<GEMM_GRID, 256, 0, stream>>>(E1, P, W2, b1, nullptr, dinv2, batch, nullptr);
    k_agge<false><<<AGG_GRID, 256, 0, stream>>>(P, csr, ndesc, dinv, batch, E2);
    // layer 3: relu(E2 + b2 + H2*dinv2) @ W3 -> H3; self terms -> pool; edges -> pool
    k_gemm<true ><<<GEMM_GRID, 256, 0, stream>>>(E2, P, W3, b2, b3, dinv2, batch, pool);
    k_agge<true ><<<AGG_GRID, 256, 0, stream>>>(P, csr, ndesc, dinv, batch, pool);

    // mean + classifier
    k_cls<<<N_GRAPHS, 64, 0, stream>>>(pool, batch, Wl, bl, (float*)d_out);
}

// Round 7
// 386.502 us; speedup vs baseline: 1.4280x; 1.4280x over previous
//
#include <hip/hip_runtime.h>
#include <hip/hip_bf16.h>

#define N_NODES   100000
#define N_EDGES   1600000
#define F_IN      64
#define HID       64
#define N_CLASSES 45
#define N_GRAPHS  256
#define SB        392         // super-buckets: bucket = dst >> 8 (0..390)
#define NPB       256         // nodes per bucket
#define CAP       4608        // fixed bucket capacity; 4608 = 72*64 (mean 4082, sigma 64 -> +8s)
#define WPB       72          // waves per bucket in k_agge (CAP/64)
#define CHUNK     4096        // edges per scatter workgroup
#define NCHUNK    391         // ceil(N_EDGES / CHUNK)
#define NZB       192         // zero-blocks in the front kernel (E1 only)
#define GEMM_GRID 3125        // N_NODES/32
#define AGGE_GRID 7056        // SB*WPB/4
#define NZB2      192         // zero-role blocks appended to agge1 (pool+E2)
#define ZLEN4_F   1600000     // E1 bytes/16  (25.6 MB)
#define ZLEN4_A   1604096     // (pool 64KB + E2 25.6MB)/16
#define COEF_GRID 1764        // SB*CAP/4 int4 slots / 256 threads

__device__ __forceinline__ float rl_f(float v, int k) {
    return __uint_as_float(__builtin_amdgcn_readlane(__float_as_uint(v), k));
}
__device__ __forceinline__ int rl_i(int v, int k) {
    return __builtin_amdgcn_readlane(v, k);
}
// fp32 <-> bf16 (RNE)
__device__ __forceinline__ unsigned short f2bf(float x) {
    unsigned u = __float_as_uint(x);
    unsigned r = u + 0x7FFFu + ((u >> 16) & 1u);
    return (unsigned short)(r >> 16);
}
__device__ __forceinline__ float bf2f(unsigned short h) {
    return __uint_as_float(((unsigned)h) << 16);
}

// ---------------- front kernel: scatter | zero(E1) | gemm1 ----------------
// payload: src(17b) | dstLow(8b)<<17
__global__ __launch_bounds__(256) void k_front(const int* __restrict__ src, const int* __restrict__ dst,
                                               int* __restrict__ bcur, int* __restrict__ binned,
                                               const float* __restrict__ x, const float* __restrict__ W1,
                                               unsigned short* __restrict__ P, float* __restrict__ zbase) {
    int bid = blockIdx.x;
    int t   = threadIdx.x;
    if (bid < NCHUNK) {
        // ---- scatter (bucket multisplit) ----
        __shared__ int stg[CHUNK];
        __shared__ unsigned short bkt[CHUNK];
        __shared__ int h[512], cur[512], off[512];
        __shared__ int ps[256];
        h[t] = 0; h[t + 256] = 0;
        __syncthreads();
        int base4 = bid * (CHUNK / 4);
        // phase 1: histogram (dst read #1)
        #pragma unroll
        for (int i = 0; i < CHUNK / 1024; i++) {
            int e4 = base4 + i * 256 + t;
            if (e4 < N_EDGES / 4) {
                int4 d = ((const int4*)dst)[e4];
                atomicAdd(&h[d.x >> 8], 1);
                atomicAdd(&h[d.y >> 8], 1);
                atomicAdd(&h[d.z >> 8], 1);
                atomicAdd(&h[d.w >> 8], 1);
            }
        }
        __syncthreads();
        // phase 2: pair-scan over 512 slots + global reservation; off = gbase - lbase
        int a0 = h[2 * t], a1 = h[2 * t + 1];
        ps[t] = a0 + a1;
        __syncthreads();
        for (int o = 1; o < 256; o <<= 1) {
            int v = (t >= o) ? ps[t - o] : 0;
            __syncthreads();
            if (t >= o) ps[t] += v;
            __syncthreads();
        }
        int pex = ps[t] - (a0 + a1);               // exclusive over pairs
        int e0 = pex, e1 = pex + a0;
        cur[2 * t] = e0; cur[2 * t + 1] = e1;
        if (2 * t < SB && a0 > 0)
            off[2 * t] = (2 * t) * CAP + atomicAdd(&bcur[2 * t], a0) - e0;
        if (2 * t + 1 < SB && a1 > 0)
            off[2 * t + 1] = (2 * t + 1) * CAP + atomicAdd(&bcur[2 * t + 1], a1) - e1;
        __syncthreads();
        int total = ps[255];                        // edges in this chunk
        // phase 3: re-read dst (+src), stage payload + bucket id
        #pragma unroll
        for (int i = 0; i < CHUNK / 1024; i++) {
            int e4 = base4 + i * 256 + t;
            if (e4 < N_EDGES / 4) {
                int4 d  = ((const int4*)dst)[e4];   // L2-hot re-read
                int4 s4 = ((const int4*)src)[e4];
                int q;
                q = atomicAdd(&cur[d.x >> 8], 1); stg[q] = s4.x | ((d.x & 255) << 17); bkt[q] = (unsigned short)(d.x >> 8);
                q = atomicAdd(&cur[d.y >> 8], 1); stg[q] = s4.y | ((d.y & 255) << 17); bkt[q] = (unsigned short)(d.y >> 8);
                q = atomicAdd(&cur[d.z >> 8], 1); stg[q] = s4.z | ((d.z & 255) << 17); bkt[q] = (unsigned short)(d.z >> 8);
                q = atomicAdd(&cur[d.w >> 8], 1); stg[q] = s4.w | ((d.w & 255) << 17); bkt[q] = (unsigned short)(d.w >> 8);
            }
        }
        __syncthreads();
        // phase 4: flat flush — coalesced LDS read, run-coalesced global write
        for (int i = t; i < total; i += 256) {
            int b = bkt[i];
            binned[off[b] + i] = stg[i];
        }
    } else if (bid < NCHUNK + NZB) {
        // ---- zero E1 ----
        float4 z = make_float4(0.f, 0.f, 0.f, 0.f);
        float4* zp = (float4*)zbase;
        int zb = bid - NCHUNK;
        for (long i = (long)zb * 256 + t; i < (long)ZLEN4_F; i += (long)NZB * 256)
            zp[i] = z;
    } else {
        // ---- gemm1: H1 = x @ W1 (bf16) ----
        int gbid = bid - NCHUNK - NZB;
        int lane = t & 63;
        int wv   = t >> 6;
        int base = gbid * 32 + wv * 8;
        float xr[8], acc[8];
        #pragma unroll
        for (int r = 0; r < 8; r++) {
            xr[r]  = x[(size_t)(base + r) * 64 + lane];
            acc[r] = 0.f;
        }
        for (int kb = 0; kb < 64; kb += 8) {
            float wb[8];
            #pragma unroll
            for (int j = 0; j < 8; j++) wb[j] = W1[(kb + j) * 64 + lane];
            #pragma unroll
            for (int j = 0; j < 8; j++) {
                #pragma unroll
                for (int r = 0; r < 8; r++)
                    acc[r] = fmaf(rl_f(xr[r], kb + j), wb[j], acc[r]);
            }
        }
        #pragma unroll
        for (int r = 0; r < 8; r++)
            P[(size_t)(base + r) * 64 + lane] = f2bf(acc[r]);
    }
}

// ---------------- per-bucket: degrees -> dinv/dinv2 + node-sorted csr fill ----------------
__global__ __launch_bounds__(256) void k_bcsr(const int* __restrict__ binned, const int* __restrict__ bcur,
                                              float* __restrict__ dinv, float* __restrict__ dinv2,
                                              int* __restrict__ csr) {
    __shared__ int h[NPB];
    __shared__ int ts[NPB];
    int t = threadIdx.x;
    int b = blockIdx.x;
    int nb0  = b << 8;
    int ebeg = b * CAP;
    int ecnt = bcur[b]; if (ecnt > CAP) ecnt = CAP;
    h[t] = 0;
    __syncthreads();
    for (int i = t; i < ecnt; i += 256)
        atomicAdd(&h[binned[ebeg + i] >> 17], 1);
    __syncthreads();
    int c = h[t];
    ts[t] = c;
    __syncthreads();
    for (int o = 1; o < 256; o <<= 1) {
        int v = (t >= o) ? ts[t - o] : 0;
        __syncthreads();
        if (t >= o) ts[t] += v;
        __syncthreads();
    }
    int excl = ts[t] - c + ebeg;
    int n = nb0 + t;
    if (n < N_NODES) {
        float inv = 1.0f / (float)(c + 1);         // +1 self loop
        dinv2[n] = inv;
        dinv[n]  = sqrtf(inv);
    }
    __syncthreads();
    h[t] = excl;                                   // per-node write cursor
    __syncthreads();
    for (int i = t; i < ecnt; i += 256) {
        int p = binned[ebeg + i];
        int q = atomicAdd(&h[p >> 17], 1);
        csr[q] = p;                                // keep src | dstLow<<17
    }
}

// ---------------- per-slot coefficient: coef[i] = dinv[src_i] * dinv[dst_i] ----------------
// Built once, consumed 3x by k_agge. Removes (a) the per-lane scattered dinv[src] gather
// in agge init and (b) the dinv[dst] load inside the flush (which, issued after the
// previous flush's atomic, stalled on its L2-ack due to in-order vmem retirement).
// Slots beyond a bucket's used count hold garbage payloads: indices are masked/clamped
// to stay in-bounds; the values are never consumed (rem-capped windows).
__global__ __launch_bounds__(256) void k_coef(const int* __restrict__ csr, const float* __restrict__ dinv,
                                              float* __restrict__ coef) {
    int i4 = blockIdx.x * 256 + threadIdx.x;       // int4 slot index; CAP%4==0 -> same bucket
    int b  = (i4 >> 10) * 4096 / CAP;              // not exact; compute directly instead
    b = (i4 * 4) / CAP;
    int nb0 = b << 8;
    int4 p = ((const int4*)csr)[i4];
    float4 c;
    {
        unsigned u0 = (unsigned)p.x; int s = (int)(u0 & 0x1FFFFu); int d = nb0 + (int)((u0 >> 17) & 0xFFu);
        c.x = dinv[s < N_NODES ? s : 0] * dinv[d < N_NODES ? d : 0];
    }
    {
        unsigned u0 = (unsigned)p.y; int s = (int)(u0 & 0x1FFFFu); int d = nb0 + (int)((u0 >> 17) & 0xFFu);
        c.y = dinv[s < N_NODES ? s : 0] * dinv[d < N_NODES ? d : 0];
    }
    {
        unsigned u0 = (unsigned)p.z; int s = (int)(u0 & 0x1FFFFu); int d = nb0 + (int)((u0 >> 17) & 0xFFu);
        c.z = dinv[s < N_NODES ? s : 0] * dinv[d < N_NODES ? d : 0];
    }
    {
        unsigned u0 = (unsigned)p.w; int s = (int)(u0 & 0x1FFFFu); int d = nb0 + (int)((u0 >> 17) & 0xFFu);
        c.w = dinv[s < N_NODES ? s : 0] * dinv[d < N_NODES ? d : 0];
    }
    ((float4*)coef)[i4] = c;
}

// ---------------- GEMM layers 2/3 ----------------
// xin = relu(E[n] + bprev + Hprev[n]*dinv2[n]);  Hnew = xin @ W  (bf16, in-place in P)
// POOLI (layer 3): pool[batch[n]] += bcurr + Hnew[n]*dinv2[n]
template<bool POOLI>
__global__ __launch_bounds__(256) void k_gemm(const float* __restrict__ E,
                                              unsigned short* P,            // aliased in/out (row-private)
                                              const float* __restrict__ W,
                                              const float* __restrict__ bprev,
                                              const float* __restrict__ bcurr,
                                              const float* __restrict__ dinv2,
                                              const int* __restrict__ batch,
                                              float* __restrict__ pool) {
    int lane = threadIdx.x & 63;
    int wv   = threadIdx.x >> 6;
    int base = blockIdx.x * 32 + wv * 8;           // grid exact (3125*32)
    float bp = bprev[lane];
    float xr[8], acc[8];
    #pragma unroll
    for (int r = 0; r < 8; r++) {
        int n = base + r;
        float hp = bf2f(P[(size_t)n * 64 + lane]);
        float a  = E[(size_t)n * 64 + lane] + fmaf(hp, dinv2[n], bp);
        xr[r]  = fmaxf(a, 0.f);
        acc[r] = 0.f;
    }
    for (int kb = 0; kb < 64; kb += 8) {
        float wb[8];
        #pragma unroll
        for (int j = 0; j < 8; j++) wb[j] = W[(kb + j) * 64 + lane];
        #pragma unroll
        for (int j = 0; j < 8; j++) {
            #pragma unroll
            for (int r = 0; r < 8; r++)
                acc[r] = fmaf(rl_f(xr[r], kb + j), wb[j], acc[r]);
        }
    }
    #pragma unroll
    for (int r = 0; r < 8; r++)
        P[(size_t)(base + r) * 64 + lane] = f2bf(acc[r]);
    if (POOLI) {
        float bv = bcurr[lane];
        float d2[8];
        #pragma unroll
        for (int r = 0; r < 8; r++) d2[r] = dinv2[base + r];
        int g0 = batch[base], g7 = batch[base + 7];
        if (g0 == g7) {
            float s = 0.f;
            #pragma unroll
            for (int r = 0; r < 8; r++) s += fmaf(acc[r], d2[r], bv);
            atomicAdd(&pool[g0 * 64 + lane], s);
        } else {
            #pragma unroll
            for (int r = 0; r < 8; r++) {
                int g = batch[base + r];
                atomicAdd(&pool[g * 64 + lane], fmaf(acc[r], d2[r], bv));
            }
        }
    }
}

// ---------------- Edge-parallel aggregation (bf16 gather; issue-all-64) ----------------
// Wave owns 64 csr slots (node-sorted runs within one bucket).
// Out[dst] += sum(coef[slot] * H[src])   (coef = dinv[src]*dinv[dst], precomputed).
// rem==64 fast path: ALL 64 gathers are issued before any consume/flush (sched_barrier
// pins the order). Because vmem retires in order, this guarantees no load ever waits on
// an atomic's L2-ack (r0 issued loads after flushes -> serialized), and raises per-wave
// outstanding loads 16 -> 64. Consume loop is byte-identical to the proven r0 form.
// Flush = one bare full-wave 256B atomic per run (no dinv load before it anymore).
// POOLEP: flush into pool[batch[dst]] instead (layer 3).
// ZROLE: trailing NZB2 blocks zero the pool|E2 span (rides agge1's latency shadow).
template<bool POOLEP, bool ZROLE>
__global__ __launch_bounds__(256, 5) void k_agge(const unsigned short* __restrict__ Hbuf,
                                                 const int* __restrict__ csr,
                                                 const int* __restrict__ bcur,
                                                 const float* __restrict__ coef,
                                                 const int* __restrict__ batch,
                                                 float* __restrict__ Out,
                                                 float* __restrict__ zbase) {
    int t = threadIdx.x;
    if (ZROLE && blockIdx.x >= AGGE_GRID) {
        float4 z = make_float4(0.f, 0.f, 0.f, 0.f);
        float4* zp = (float4*)zbase;
        int zb = blockIdx.x - AGGE_GRID;
        for (long i = (long)zb * 256 + t; i < (long)ZLEN4_A; i += (long)NZB2 * 256)
            zp[i] = z;
        return;
    }
    int wv   = t >> 6;
    int lane = t & 63;
    int wid  = blockIdx.x * 4 + wv;                // 0 .. SB*WPB-1
    int b    = wid / WPB;
    int lw   = wid - b * WPB;
    int used = bcur[b]; if (used > CAP) used = CAP;
    int e0   = lw * 64;
    int rem  = used - e0;
    if (rem <= 0) return;
    if (rem > 64) rem = 64;
    int base = b * CAP + e0;

    int p = 0;
    float cv = 0.f;
    if (lane < rem) {
        p  = csr[base + lane];                     // coalesced 256B
        cv = coef[base + lane];                    // coalesced 256B (no gather)
    }
    int dv = p >> 17;                              // dstLow (8b)

    auto flush1 = [&](int dl, float a) {
        int dst = (b << 8) + dl;
        if (dst < N_NODES) {
            if (POOLEP) {
                int g = batch[dst];                // uniform load
                atomicAdd(&Out[g * 64 + lane], a);
            } else {
                atomicAdd(&Out[(size_t)dst * 64 + lane], a);
            }
        }
    };

    if (rem == 64) {
        // ---- issue-all-64 fast path ----
        const unsigned short* Hl = Hbuf + lane;
        unsigned short u[64];
        #pragma unroll
        for (int i = 0; i < 64; i++) {             // 64 pure loads, nothing between them
            unsigned s = (unsigned)(rl_i(p, i) & 0x1FFFF);
            u[i] = Hl[(size_t)s << 6];
        }
        __builtin_amdgcn_sched_barrier(0);         // pin: no consume/flush hoists above
        int dprev = rl_i(dv, 0);
        float acc = 0.f;
        #pragma unroll
        for (int i = 0; i < 64; i++) {             // proven r0 consume, flushes inline
            int   d = rl_i(dv, i);
            float c = rl_f(cv, i);
            if (d != dprev) { flush1(dprev, acc); acc = 0.f; dprev = d; }
            acc = fmaf(bf2f(u[i]), c, acc);
        }
        flush1(dprev, acc);
    } else {
        // ---- partial-window path: r0 proven loop ----
        int sv = p & 0x1FFFF;
        int dprev = rl_i(dv, 0);
        float acc = 0.f;
        int j = 0;
        for (; j + 16 <= rem; j += 16) {
            unsigned short u[16];
            #pragma unroll
            for (int i = 0; i < 16; i++) {         // 16 gathers issued up front
                int s = rl_i(sv, j + i);
                u[i] = Hbuf[(size_t)s * 64 + lane];
            }
            #pragma unroll
            for (int i = 0; i < 16; i++) {
                int   d = rl_i(dv, j + i);
                float c = rl_f(cv, j + i);
                if (d != dprev) { flush1(dprev, acc); acc = 0.f; dprev = d; }
                acc = fmaf(bf2f(u[i]), c, acc);
            }
        }
        for (; j < rem; j++) {
            int   s0 = rl_i(sv, j);
            float c0 = rl_f(cv, j);
            int   d0 = rl_i(dv, j);
            unsigned short u0 = Hbuf[(size_t)s0 * 64 + lane];
            if (d0 != dprev) { flush1(dprev, acc); acc = 0.f; dprev = d0; }
            acc = fmaf(bf2f(u0), c0, acc);
        }
        flush1(dprev, acc);
    }
}

// ---------------- mean + classifier ----------------
__device__ __forceinline__ int lbound(const int* __restrict__ a, int n, int v) {
    int lo = 0, hi = n;
    while (lo < hi) { int m = (lo + hi) >> 1; if (a[m] < v) lo = m + 1; else hi = m; }
    return lo;
}

__global__ __launch_bounds__(64) void k_cls(const float* __restrict__ pool, const int* __restrict__ batch,
                                            const float* __restrict__ Wl, const float* __restrict__ bl,
                                            float* __restrict__ out) {
    __shared__ float pm[64];
    __shared__ int bounds[2];
    int g = blockIdx.x;
    int t = threadIdx.x;
    if (t < 2) bounds[t] = lbound(batch, N_NODES, g + t);
    __syncthreads();
    float cnt = (float)(bounds[1] - bounds[0]);
    pm[t] = pool[g * 64 + t] / fmaxf(cnt, 1.0f);
    __syncthreads();
    if (t < N_CLASSES) {
        float o = bl[t];
        #pragma unroll
        for (int k = 0; k < HID; k++) o = fmaf(pm[k], Wl[k * N_CLASSES + t], o);
        out[g * N_CLASSES + t] = o;
    }
}

// ---------------- launch ----------------

extern "C" void kernel_launch(void* const* d_in, const int* in_sizes, int n_in,
                              void* d_out, int out_size, void* d_ws, size_t ws_size,
                              hipStream_t stream) {
    const float* x     = (const float*)d_in[0];
    const int*   eidx  = (const int*)  d_in[1];
    const int*   batch = (const int*)  d_in[2];
    const float* W1 = (const float*)d_in[3];
    const float* b1 = (const float*)d_in[4];
    const float* W2 = (const float*)d_in[5];
    const float* b2 = (const float*)d_in[6];
    const float* W3 = (const float*)d_in[7];
    const float* b3 = (const float*)d_in[8];
    const float* Wl = (const float*)d_in[9];
    const float* bl = (const float*)d_in[10];
    const int* src = eidx;
    const int* dst = eidx + N_EDGES;

    char* p = (char*)d_ws;
    auto alloc = [&](size_t bytes) -> void* {
        void* r = (void*)p;
        p += (bytes + 255) & ~(size_t)255;
        return r;
    };
    float* dinv  = (float*)alloc((size_t)N_NODES * 4);
    float* dinv2 = (float*)alloc((size_t)N_NODES * 4);
    int*   csr   = (int*)  alloc((size_t)SB * CAP * 4);
    unsigned short* P = (unsigned short*)alloc((size_t)N_NODES * 64 * 2);  // bf16 H
    float* E1    = (float*)alloc((size_t)N_NODES * 64 * 4);   // edge sums L1
    float* pool  = (float*)alloc((size_t)N_GRAPHS * 64 * 4);  // contiguous after E1
    float* E2    = (float*)alloc((size_t)N_NODES * 64 * 4);   // contiguous after pool
    int*   bcur  = (int*)  alloc((size_t)SB * 4);
    int*   binned = (int*) alloc((size_t)SB * CAP * 4);
    float* coef  = (float*)alloc((size_t)SB * CAP * 4);       // dinv[src]*dinv[dst] per slot

    const int front_grid = NCHUNK + NZB + GEMM_GRID;

    // ---- front: scatter | zero(E1) | gemm1 (all independent) ----
    hipMemsetAsync(bcur, 0, (size_t)SB * 4, stream);
    k_front<<<front_grid, 256, 0, stream>>>(src, dst, bcur, binned, x, W1, P, E1);
    k_bcsr <<<SB, 256, 0, stream>>>(binned, bcur, dinv, dinv2, csr);
    k_coef <<<COEF_GRID, 256, 0, stream>>>(csr, dinv, coef);

    // layer 1 edges: H1 gathers -> E1 ; trailing blocks zero pool|E2
    k_agge<false, true ><<<AGGE_GRID + NZB2, 256, 0, stream>>>(P, csr, bcur, coef, batch, E1, pool);
    // layer 2: relu(E1 + b1 + H1*dinv2) @ W2 -> H2 (in-place in P); edges -> E2
    k_gemm<false><<<GEMM_GRID, 256, 0, stream>>>(E1, P, W2, b1, nullptr, dinv2, batch, nullptr);
    k_agge<false, false><<<AGGE_GRID, 256, 0, stream>>>(P, csr, bcur, coef, batch, E2, nullptr);
    // layer 3: relu(E2 + b2 + H2*dinv2) @ W3 -> H3; self terms -> pool; edges -> pool
    k_gemm<true ><<<GEMM_GRID, 256, 0, stream>>>(E2, P, W3, b2, b3, dinv2, batch, pool);
    k_agge<true , false><<<AGGE_GRID, 256, 0, stream>>>(P, csr, bcur, coef, batch, pool, nullptr);

    // mean + classifier
    k_cls<<<N_GRAPHS, 64, 0, stream>>>(pool, batch, Wl, bl, (float*)d_out);
}

// Round 9
// 363.522 us; speedup vs baseline: 1.5182x; 1.0632x over previous
//
#include <hip/hip_runtime.h>
#include <hip/hip_bf16.h>

#define N_NODES   100000
#define N_EDGES   1600000
#define F_IN      64
#define HID       64
#define N_CLASSES 45
#define N_GRAPHS  256
#define SB        392         // super-buckets: bucket = dst >> 8 (0..390)
#define NPB       256         // nodes per bucket
#define CAP       4608        // fixed bucket capacity; 4608 = 72*64 (mean 4082, sigma 64 -> +8s)
#define WPB       72          // waves per bucket in k_agge (CAP/64)
#define CHUNK     4096        // edges per scatter workgroup
#define NCHUNK    391         // ceil(N_EDGES / CHUNK)
#define NZB       192         // zero-blocks in the front kernel (E1 only)
#define GEMM_GRID 3125        // N_NODES/32
#define AGGE_GRID 7056        // SB*WPB/4
#define NZB2      192         // zero-role blocks appended to agge1 (pool+E2)
#define ZLEN4_F   1600000     // E1 bytes/16  (25.6 MB)
#define ZLEN4_A   1604096     // (pool 64KB + E2 25.6MB)/16

__device__ __forceinline__ float rl_f(float v, int k) {
    return __uint_as_float(__builtin_amdgcn_readlane(__float_as_uint(v), k));
}
__device__ __forceinline__ int rl_i(int v, int k) {
    return __builtin_amdgcn_readlane(v, k);
}
// fp32 <-> bf16 (RNE)
__device__ __forceinline__ unsigned short f2bf(float x) {
    unsigned u = __float_as_uint(x);
    unsigned r = u + 0x7FFFu + ((u >> 16) & 1u);
    return (unsigned short)(r >> 16);
}
__device__ __forceinline__ float bf2f(unsigned short h) {
    return __uint_as_float(((unsigned)h) << 16);
}
// scale a packed bf16 pair by dv (unpack-mul-repack)
__device__ __forceinline__ unsigned scale2(unsigned u, float dv) {
    float lo = __uint_as_float(u << 16) * dv;
    float hi = __uint_as_float(u & 0xFFFF0000u) * dv;
    return (((unsigned)f2bf(hi)) << 16) | (unsigned)f2bf(lo);
}

// ---------------- front kernel: scatter | zero(E1) | gemm1 ----------------
// payload: src(17b) | dstLow(8b)<<17
__global__ __launch_bounds__(256) void k_front(const int* __restrict__ src, const int* __restrict__ dst,
                                               int* __restrict__ bcur, int* __restrict__ binned,
                                               const float* __restrict__ x, const float* __restrict__ W1,
                                               unsigned short* __restrict__ P, float* __restrict__ zbase) {
    int bid = blockIdx.x;
    int t   = threadIdx.x;
    if (bid < NCHUNK) {
        // ---- scatter (bucket multisplit) ----
        __shared__ int stg[CHUNK];
        __shared__ unsigned short bkt[CHUNK];
        __shared__ int h[512], cur[512], off[512];
        __shared__ int ps[256];
        h[t] = 0; h[t + 256] = 0;
        __syncthreads();
        int base4 = bid * (CHUNK / 4);
        // phase 1: histogram (dst read #1)
        #pragma unroll
        for (int i = 0; i < CHUNK / 1024; i++) {
            int e4 = base4 + i * 256 + t;
            if (e4 < N_EDGES / 4) {
                int4 d = ((const int4*)dst)[e4];
                atomicAdd(&h[d.x >> 8], 1);
                atomicAdd(&h[d.y >> 8], 1);
                atomicAdd(&h[d.z >> 8], 1);
                atomicAdd(&h[d.w >> 8], 1);
            }
        }
        __syncthreads();
        // phase 2: pair-scan over 512 slots + global reservation; off = gbase - lbase
        int a0 = h[2 * t], a1 = h[2 * t + 1];
        ps[t] = a0 + a1;
        __syncthreads();
        for (int o = 1; o < 256; o <<= 1) {
            int v = (t >= o) ? ps[t - o] : 0;
            __syncthreads();
            if (t >= o) ps[t] += v;
            __syncthreads();
        }
        int pex = ps[t] - (a0 + a1);               // exclusive over pairs
        int e0 = pex, e1 = pex + a0;
        cur[2 * t] = e0; cur[2 * t + 1] = e1;
        if (2 * t < SB && a0 > 0)
            off[2 * t] = (2 * t) * CAP + atomicAdd(&bcur[2 * t], a0) - e0;
        if (2 * t + 1 < SB && a1 > 0)
            off[2 * t + 1] = (2 * t + 1) * CAP + atomicAdd(&bcur[2 * t + 1], a1) - e1;
        __syncthreads();
        int total = ps[255];                        // edges in this chunk
        // phase 3: re-read dst (+src), stage payload + bucket id
        #pragma unroll
        for (int i = 0; i < CHUNK / 1024; i++) {
            int e4 = base4 + i * 256 + t;
            if (e4 < N_EDGES / 4) {
                int4 d  = ((const int4*)dst)[e4];   // L2-hot re-read
                int4 s4 = ((const int4*)src)[e4];
                int q;
                q = atomicAdd(&cur[d.x >> 8], 1); stg[q] = s4.x | ((d.x & 255) << 17); bkt[q] = (unsigned short)(d.x >> 8);
                q = atomicAdd(&cur[d.y >> 8], 1); stg[q] = s4.y | ((d.y & 255) << 17); bkt[q] = (unsigned short)(d.y >> 8);
                q = atomicAdd(&cur[d.z >> 8], 1); stg[q] = s4.z | ((d.z & 255) << 17); bkt[q] = (unsigned short)(d.z >> 8);
                q = atomicAdd(&cur[d.w >> 8], 1); stg[q] = s4.w | ((d.w & 255) << 17); bkt[q] = (unsigned short)(d.w >> 8);
            }
        }
        __syncthreads();
        // phase 4: flat flush — coalesced LDS read, run-coalesced global write
        for (int i = t; i < total; i += 256) {
            int b = bkt[i];
            binned[off[b] + i] = stg[i];
        }
    } else if (bid < NCHUNK + NZB) {
        // ---- zero E1 ----
        float4 z = make_float4(0.f, 0.f, 0.f, 0.f);
        float4* zp = (float4*)zbase;
        int zb = bid - NCHUNK;
        for (long i = (long)zb * 256 + t; i < (long)ZLEN4_F; i += (long)NZB * 256)
            zp[i] = z;
    } else {
        // ---- gemm1: H1 = x @ W1 (bf16, unscaled; k_bcsr scales by dinv afterwards) ----
        int gbid = bid - NCHUNK - NZB;
        int lane = t & 63;
        int wv   = t >> 6;
        int base = gbid * 32 + wv * 8;
        float xr[8], acc[8];
        #pragma unroll
        for (int r = 0; r < 8; r++) {
            xr[r]  = x[(size_t)(base + r) * 64 + lane];
            acc[r] = 0.f;
        }
        for (int kb = 0; kb < 64; kb += 8) {
            float wb[8];
            #pragma unroll
            for (int j = 0; j < 8; j++) wb[j] = W1[(kb + j) * 64 + lane];
            #pragma unroll
            for (int j = 0; j < 8; j++) {
                #pragma unroll
                for (int r = 0; r < 8; r++)
                    acc[r] = fmaf(rl_f(xr[r], kb + j), wb[j], acc[r]);
            }
        }
        #pragma unroll
        for (int r = 0; r < 8; r++)
            P[(size_t)(base + r) * 64 + lane] = f2bf(acc[r]);
    }
}

// ---------------- per-bucket: degrees -> dinv/dinv2 + node-sorted csr fill + P pre-scale ----------------
// P rows are scaled in place by dinv[n] (coalesced R+W, ~25.6MB total). This removes the
// per-edge dinv[src] work from k_agge entirely: the aggregation becomes
// Out[dst] = dinv[dst] * sum(Pscaled[src]), with no scattered coefficient gather and no
// per-edge multiply. k_gemm consumes the scaled form (self term uses dinv, not dinv2).
__global__ __launch_bounds__(256) void k_bcsr(const int* __restrict__ binned, const int* __restrict__ bcur,
                                              float* __restrict__ dinv, float* __restrict__ dinv2,
                                              int* __restrict__ csr, unsigned short* __restrict__ P) {
    __shared__ int h[NPB];
    __shared__ int ts[NPB];
    __shared__ float sdv[NPB];
    int t = threadIdx.x;
    int b = blockIdx.x;
    int nb0  = b << 8;
    int ebeg = b * CAP;
    int ecnt = bcur[b]; if (ecnt > CAP) ecnt = CAP;
    h[t] = 0;
    __syncthreads();
    for (int i = t; i < ecnt; i += 256)
        atomicAdd(&h[binned[ebeg + i] >> 17], 1);
    __syncthreads();
    int c = h[t];
    ts[t] = c;
    __syncthreads();
    for (int o = 1; o < 256; o <<= 1) {
        int v = (t >= o) ? ts[t - o] : 0;
        __syncthreads();
        if (t >= o) ts[t] += v;
        __syncthreads();
    }
    int excl = ts[t] - c + ebeg;
    int n = nb0 + t;
    float dval = 0.f;
    if (n < N_NODES) {
        float inv = 1.0f / (float)(c + 1);         // +1 self loop
        dinv2[n] = inv;
        dval     = sqrtf(inv);
        dinv[n]  = dval;
    }
    sdv[t] = dval;
    __syncthreads();
    h[t] = excl;                                   // per-node write cursor
    __syncthreads();
    for (int i = t; i < ecnt; i += 256) {
        int p = binned[ebeg + i];
        int q = atomicAdd(&h[p >> 17], 1);
        csr[q] = p;                                // keep src | dstLow<<17
    }
    // ---- scale this bucket's P rows by dinv (8 uint4 = 64 bf16 per row) ----
    for (int i = t; i < NPB * 8; i += 256) {
        int row = i >> 3;
        int nn  = nb0 + row;
        if (nn >= N_NODES) break;                  // row monotone in i per thread
        float dv = sdv[row];
        uint4* pp = (uint4*)P + (size_t)nn * 8 + (i & 7);
        uint4 v = *pp;
        v.x = scale2(v.x, dv); v.y = scale2(v.y, dv);
        v.z = scale2(v.z, dv); v.w = scale2(v.w, dv);
        *pp = v;
    }
}

// ---------------- GEMM layers 2/3 ----------------
// P holds SCALED H (Hprev * dinv[n], bf16).
// xin = relu(E[n] + bprev + Pscaled[n]*dinv[n]);  (== E + b + Hprev*dinv2)
// Hnew = xin @ W; store P = f2bf(Hnew * dinv[n])  (scaled for the next aggregation)
// POOLI (layer 3): pool[batch[n]] += bcurr + Hnew[n]*dinv2[n]  (uses unscaled register acc)
template<bool POOLI>
__global__ __launch_bounds__(256) void k_gemm(const float* __restrict__ E,
                                              unsigned short* P,            // aliased in/out (row-private)
                                              const float* __restrict__ W,
                                              const float* __restrict__ bprev,
                                              const float* __restrict__ bcurr,
                                              const float* __restrict__ dinv,
                                              const float* __restrict__ dinv2,
                                              const int* __restrict__ batch,
                                              float* __restrict__ pool) {
    int lane = threadIdx.x & 63;
    int wv   = threadIdx.x >> 6;
    int base = blockIdx.x * 32 + wv * 8;           // grid exact (3125*32)
    float bp = bprev[lane];
    float xr[8], acc[8], dn[8];
    #pragma unroll
    for (int r = 0; r < 8; r++) dn[r] = dinv[base + r];
    #pragma unroll
    for (int r = 0; r < 8; r++) {
        int n = base + r;
        float hp = bf2f(P[(size_t)n * 64 + lane]); // scaled Hprev
        float a  = E[(size_t)n * 64 + lane] + fmaf(hp, dn[r], bp);
        xr[r]  = fmaxf(a, 0.f);
        acc[r] = 0.f;
    }
    for (int kb = 0; kb < 64; kb += 8) {
        float wb[8];
        #pragma unroll
        for (int j = 0; j < 8; j++) wb[j] = W[(kb + j) * 64 + lane];
        #pragma unroll
        for (int j = 0; j < 8; j++) {
            #pragma unroll
            for (int r = 0; r < 8; r++)
                acc[r] = fmaf(rl_f(xr[r], kb + j), wb[j], acc[r]);
        }
    }
    #pragma unroll
    for (int r = 0; r < 8; r++)
        P[(size_t)(base + r) * 64 + lane] = f2bf(acc[r] * dn[r]);   // store scaled
    if (POOLI) {
        float bv = bcurr[lane];
        float d2[8];
        #pragma unroll
        for (int r = 0; r < 8; r++) d2[r] = dinv2[base + r];
        int g0 = batch[base], g7 = batch[base + 7];
        if (g0 == g7) {
            float s = 0.f;
            #pragma unroll
            for (int r = 0; r < 8; r++) s += fmaf(acc[r], d2[r], bv);
            atomicAdd(&pool[g0 * 64 + lane], s);
        } else {
            #pragma unroll
            for (int r = 0; r < 8; r++) {
                int g = batch[base + r];
                atomicAdd(&pool[g * 64 + lane], fmaf(acc[r], d2[r], bv));
            }
        }
    }
}

// ---------------- Edge-parallel aggregation (bf16 gather; pre-scaled H, scalar run mask) ----------------
// Wave owns 64 csr slots (node-sorted runs within one bucket).
// Out[dst] += dinv[dst] * sum(Pscaled[src])   (atomic; Out pre-zeroed)
// vs r0: (1) no per-edge coefficient — H is pre-scaled by dinv[src], so the scattered
// dinv gather in window init and the per-edge rl_f+fma disappear (consume = shift+add,
// 2 VALU/edge); (2) run boundaries come from a wave-uniform 64-bit ballot mask computed
// once per window — per-edge detection is an SALU bit-test + scalar branch (zero VALU).
// Memory-op sequence (csr load, 16-gather batches, inline full-wave 256B atomic per run)
// is byte-identical to the proven r0 form.
// POOLEP: flush into pool[batch[dst]] instead (layer 3).
// ZROLE: trailing NZB2 blocks zero the pool|E2 span (rides agge1's latency shadow).
template<bool POOLEP, bool ZROLE>
__global__ __launch_bounds__(256, 8) void k_agge(const unsigned short* __restrict__ Hbuf,
                                                 const int* __restrict__ csr,
                                                 const int* __restrict__ bcur,
                                                 const float* __restrict__ dinv,
                                                 const int* __restrict__ batch,
                                                 float* __restrict__ Out,
                                                 float* __restrict__ zbase) {
    int t = threadIdx.x;
    if (ZROLE && blockIdx.x >= AGGE_GRID) {
        float4 z = make_float4(0.f, 0.f, 0.f, 0.f);
        float4* zp = (float4*)zbase;
        int zb = blockIdx.x - AGGE_GRID;
        for (long i = (long)zb * 256 + t; i < (long)ZLEN4_A; i += (long)NZB2 * 256)
            zp[i] = z;
        return;
    }
    int wv   = t >> 6;
    int lane = t & 63;
    int wid  = blockIdx.x * 4 + wv;                // 0 .. SB*WPB-1
    int b    = wid / WPB;
    int lw   = wid - b * WPB;
    int used = bcur[b]; if (used > CAP) used = CAP;
    int e0   = lw * 64;
    int rem  = used - e0;
    if (rem <= 0) return;
    if (rem > 64) rem = 64;
    int base = b * CAP + e0;

    int p = 0;
    if (lane < rem) p = csr[base + lane];          // coalesced 256B (only load in init)
    int sv = p & 0x1FFFF;
    int dv = p >> 17;                              // dstLow (8b)

    // wave-uniform run-start mask (bit i: slot i starts a new dst run); bit 0 cleared
    int dvp = __shfl_up(dv, 1);
    unsigned long long m0 = __ballot(dv != dvp);
    unsigned mlo = __builtin_amdgcn_readfirstlane((unsigned)m0);
    unsigned mhi = __builtin_amdgcn_readfirstlane((unsigned)(m0 >> 32));
    unsigned long long mask = ((((unsigned long long)mhi) << 32) | mlo) & ~1ull;

    auto flush1 = [&](int dl, float a) {
        int dst = (b << 8) + dl;
        if (dst < N_NODES) {
            float val = dinv[dst] * a;             // uniform load
            if (POOLEP) {
                int g = batch[dst];                // uniform load
                atomicAdd(&Out[g * 64 + lane], val);
            } else {
                atomicAdd(&Out[(size_t)dst * 64 + lane], val);
            }
        }
    };

    int cur = rl_i(dv, 0);
    float acc = 0.f;
    int j = 0;
    for (; j + 16 <= rem; j += 16) {
        unsigned short u[16];
        #pragma unroll
        for (int i = 0; i < 16; i++) {             // 16 gathers issued up front (r0 form)
            int s = rl_i(sv, j + i);
            u[i] = Hbuf[(size_t)s * 64 + lane];
        }
        #pragma unroll
        for (int i = 0; i < 16; i++) {
            if ((mask >> (j + i)) & 1) {           // scalar bit-test + scalar branch
                flush1(cur, acc); acc = 0.f; cur = rl_i(dv, j + i);
            }
            acc += bf2f(u[i]);                     // 2 VALU/edge
        }
    }
    for (; j < rem; j++) {
        int s0 = rl_i(sv, j);
        unsigned short u0 = Hbuf[(size_t)s0 * 64 + lane];
        if ((mask >> j) & 1) { flush1(cur, acc); acc = 0.f; cur = rl_i(dv, j); }
        acc += bf2f(u0);
    }
    flush1(cur, acc);
}

// ---------------- mean + classifier ----------------
__device__ __forceinline__ int lbound(const int* __restrict__ a, int n, int v) {
    int lo = 0, hi = n;
    while (lo < hi) { int m = (lo + hi) >> 1; if (a[m] < v) lo = m + 1; else hi = m; }
    return lo;
}

__global__ __launch_bounds__(64) void k_cls(const float* __restrict__ pool, const int* __restrict__ batch,
                                            const float* __restrict__ Wl, const float* __restrict__ bl,
                                            float* __restrict__ out) {
    __shared__ float pm[64];
    __shared__ int bounds[2];
    int g = blockIdx.x;
    int t = threadIdx.x;
    if (t < 2) bounds[t] = lbound(batch, N_NODES, g + t);
    __syncthreads();
    float cnt = (float)(bounds[1] - bounds[0]);
    pm[t] = pool[g * 64 + t] / fmaxf(cnt, 1.0f);
    __syncthreads();
    if (t < N_CLASSES) {
        float o = bl[t];
        #pragma unroll
        for (int k = 0; k < HID; k++) o = fmaf(pm[k], Wl[k * N_CLASSES + t], o);
        out[g * N_CLASSES + t] = o;
    }
}

// ---------------- launch ----------------

extern "C" void kernel_launch(void* const* d_in, const int* in_sizes, int n_in,
                              void* d_out, int out_size, void* d_ws, size_t ws_size,
                              hipStream_t stream) {
    const float* x     = (const float*)d_in[0];
    const int*   eidx  = (const int*)  d_in[1];
    const int*   batch = (const int*)  d_in[2];
    const float* W1 = (const float*)d_in[3];
    const float* b1 = (const float*)d_in[4];
    const float* W2 = (const float*)d_in[5];
    const float* b2 = (const float*)d_in[6];
    const float* W3 = (const float*)d_in[7];
    const float* b3 = (const float*)d_in[8];
    const float* Wl = (const float*)d_in[9];
    const float* bl = (const float*)d_in[10];
    const int* src = eidx;
    const int* dst = eidx + N_EDGES;

    char* p = (char*)d_ws;
    auto alloc = [&](size_t bytes) -> void* {
        void* r = (void*)p;
        p += (bytes + 255) & ~(size_t)255;
        return r;
    };
    float* dinv  = (float*)alloc((size_t)N_NODES * 4);
    float* dinv2 = (float*)alloc((size_t)N_NODES * 4);
    int*   csr   = (int*)  alloc((size_t)SB * CAP * 4);
    unsigned short* P = (unsigned short*)alloc((size_t)N_NODES * 64 * 2);  // bf16 H (scaled)
    float* E1    = (float*)alloc((size_t)N_NODES * 64 * 4);   // edge sums L1
    float* pool  = (float*)alloc((size_t)N_GRAPHS * 64 * 4);  // contiguous after E1
    float* E2    = (float*)alloc((size_t)N_NODES * 64 * 4);   // contiguous after pool
    int*   bcur  = (int*)  alloc((size_t)SB * 4);
    int*   binned = (int*) alloc((size_t)SB * CAP * 4);

    const int front_grid = NCHUNK + NZB + GEMM_GRID;

    // ---- front: scatter | zero(E1) | gemm1 (all independent) ----
    hipMemsetAsync(bcur, 0, (size_t)SB * 4, stream);
    k_front<<<front_grid, 256, 0, stream>>>(src, dst, bcur, binned, x, W1, P, E1);
    // bcsr: degrees + csr fill + in-place scale P1 *= dinv
    k_bcsr <<<SB, 256, 0, stream>>>(binned, bcur, dinv, dinv2, csr, P);

    // layer 1 edges: scaled-H1 gathers -> E1 ; trailing blocks zero pool|E2
    k_agge<false, true ><<<AGGE_GRID + NZB2, 256, 0, stream>>>(P, csr, bcur, dinv, batch, E1, pool);
    // layer 2: relu(E1 + b1 + Ps*dinv) @ W2 -> H2 (scaled, in-place in P); edges -> E2
    k_gemm<false><<<GEMM_GRID, 256, 0, stream>>>(E1, P, W2, b1, nullptr, dinv, dinv2, batch, nullptr);
    k_agge<false, false><<<AGGE_GRID, 256, 0, stream>>>(P, csr, bcur, dinv, batch, E2, nullptr);
    // layer 3: relu(E2 + b2 + Ps*dinv) @ W3 -> H3; self terms -> pool; edges -> pool
    k_gemm<true ><<<GEMM_GRID, 256, 0, stream>>>(E2, P, W3, b2, b3, dinv, dinv2, batch, pool);
    k_agge<true , false><<<AGGE_GRID, 256, 0, stream>>>(P, csr, bcur, dinv, batch, pool, nullptr);

    // mean + classifier
    k_cls<<<N_GRAPHS, 64, 0, stream>>>(pool, batch, Wl, bl, (float*)d_out);
}

// Round 10
// 355.335 us; speedup vs baseline: 1.5532x; 1.0230x over previous
//
#include <hip/hip_runtime.h>
#include <hip/hip_bf16.h>

#define N_NODES   100000
#define N_EDGES   1600000
#define F_IN      64
#define HID       64
#define N_CLASSES 45
#define N_GRAPHS  256
#define SB        392         // super-buckets: bucket = dst >> 8 (0..390)
#define NPB       256         // nodes per bucket
#define CAP       4608        // fixed bucket capacity; 4608 = 72*64 (mean 4082, sigma 64 -> +8s)
#define WPB       72          // waves per bucket in k_agge (CAP/64)
#define CHUNK     4096        // edges per scatter workgroup
#define NCHUNK    391         // ceil(N_EDGES / CHUNK)
#define NZB       192         // zero-blocks in the front kernel (E1 only)
#define GEMM_GRID 3125        // N_NODES/32
#define AGGE_GRID 7056        // SB*WPB/4
#define NZB2      192         // zero-role blocks appended to agge1 (pool+E2)
#define ZLEN4_F   1600000     // E1 bytes/16  (25.6 MB)
#define ZLEN4_A   1604096     // (pool 64KB + E2 25.6MB)/16

__device__ __forceinline__ float rl_f(float v, int k) {
    return __uint_as_float(__builtin_amdgcn_readlane(__float_as_uint(v), k));
}
__device__ __forceinline__ int rl_i(int v, int k) {
    return __builtin_amdgcn_readlane(v, k);
}
// fp32 <-> bf16 (RNE)
__device__ __forceinline__ unsigned short f2bf(float x) {
    unsigned u = __float_as_uint(x);
    unsigned r = u + 0x7FFFu + ((u >> 16) & 1u);
    return (unsigned short)(r >> 16);
}
__device__ __forceinline__ float bf2f(unsigned short h) {
    return __uint_as_float(((unsigned)h) << 16);
}
// scale a packed bf16 pair by dv (unpack-mul-repack)
__device__ __forceinline__ unsigned scale2(unsigned u, float dv) {
    float lo = __uint_as_float(u << 16) * dv;
    float hi = __uint_as_float(u & 0xFFFF0000u) * dv;
    return (((unsigned)f2bf(hi)) << 16) | (unsigned)f2bf(lo);
}

// ---------------- front kernel: scatter | zero(E1) | gemm1 ----------------
// payload: src(17b) | dstLow(8b)<<17
__global__ __launch_bounds__(256) void k_front(const int* __restrict__ src, const int* __restrict__ dst,
                                               int* __restrict__ bcur, int* __restrict__ binned,
                                               const float* __restrict__ x, const float* __restrict__ W1,
                                               unsigned short* __restrict__ P, float* __restrict__ zbase) {
    int bid = blockIdx.x;
    int t   = threadIdx.x;
    if (bid < NCHUNK) {
        // ---- scatter (bucket multisplit) ----
        __shared__ int stg[CHUNK];
        __shared__ unsigned short bkt[CHUNK];
        __shared__ int h[512], cur[512], off[512];
        __shared__ int ps[256];
        h[t] = 0; h[t + 256] = 0;
        __syncthreads();
        int base4 = bid * (CHUNK / 4);
        // phase 1: histogram (dst read #1)
        #pragma unroll
        for (int i = 0; i < CHUNK / 1024; i++) {
            int e4 = base4 + i * 256 + t;
            if (e4 < N_EDGES / 4) {
                int4 d = ((const int4*)dst)[e4];
                atomicAdd(&h[d.x >> 8], 1);
                atomicAdd(&h[d.y >> 8], 1);
                atomicAdd(&h[d.z >> 8], 1);
                atomicAdd(&h[d.w >> 8], 1);
            }
        }
        __syncthreads();
        // phase 2: pair-scan over 512 slots + global reservation; off = gbase - lbase
        int a0 = h[2 * t], a1 = h[2 * t + 1];
        ps[t] = a0 + a1;
        __syncthreads();
        for (int o = 1; o < 256; o <<= 1) {
            int v = (t >= o) ? ps[t - o] : 0;
            __syncthreads();
            if (t >= o) ps[t] += v;
            __syncthreads();
        }
        int pex = ps[t] - (a0 + a1);               // exclusive over pairs
        int e0 = pex, e1 = pex + a0;
        cur[2 * t] = e0; cur[2 * t + 1] = e1;
        if (2 * t < SB && a0 > 0)
            off[2 * t] = (2 * t) * CAP + atomicAdd(&bcur[2 * t], a0) - e0;
        if (2 * t + 1 < SB && a1 > 0)
            off[2 * t + 1] = (2 * t + 1) * CAP + atomicAdd(&bcur[2 * t + 1], a1) - e1;
        __syncthreads();
        int total = ps[255];                        // edges in this chunk
        // phase 3: re-read dst (+src), stage payload + bucket id
        #pragma unroll
        for (int i = 0; i < CHUNK / 1024; i++) {
            int e4 = base4 + i * 256 + t;
            if (e4 < N_EDGES / 4) {
                int4 d  = ((const int4*)dst)[e4];   // L2-hot re-read
                int4 s4 = ((const int4*)src)[e4];
                int q;
                q = atomicAdd(&cur[d.x >> 8], 1); stg[q] = s4.x | ((d.x & 255) << 17); bkt[q] = (unsigned short)(d.x >> 8);
                q = atomicAdd(&cur[d.y >> 8], 1); stg[q] = s4.y | ((d.y & 255) << 17); bkt[q] = (unsigned short)(d.y >> 8);
                q = atomicAdd(&cur[d.z >> 8], 1); stg[q] = s4.z | ((d.z & 255) << 17); bkt[q] = (unsigned short)(d.z >> 8);
                q = atomicAdd(&cur[d.w >> 8], 1); stg[q] = s4.w | ((d.w & 255) << 17); bkt[q] = (unsigned short)(d.w >> 8);
            }
        }
        __syncthreads();
        // phase 4: flat flush — coalesced LDS read, run-coalesced global write
        for (int i = t; i < total; i += 256) {
            int b = bkt[i];
            binned[off[b] + i] = stg[i];
        }
    } else if (bid < NCHUNK + NZB) {
        // ---- zero E1 ----
        float4 z = make_float4(0.f, 0.f, 0.f, 0.f);
        float4* zp = (float4*)zbase;
        int zb = bid - NCHUNK;
        for (long i = (long)zb * 256 + t; i < (long)ZLEN4_F; i += (long)NZB * 256)
            zp[i] = z;
    } else {
        // ---- gemm1: H1 = x @ W1 (bf16, unscaled; k_bcsr scales by dinv afterwards) ----
        int gbid = bid - NCHUNK - NZB;
        int lane = t & 63;
        int wv   = t >> 6;
        int base = gbid * 32 + wv * 8;
        float xr[8], acc[8];
        #pragma unroll
        for (int r = 0; r < 8; r++) {
            xr[r]  = x[(size_t)(base + r) * 64 + lane];
            acc[r] = 0.f;
        }
        for (int kb = 0; kb < 64; kb += 8) {
            float wb[8];
            #pragma unroll
            for (int j = 0; j < 8; j++) wb[j] = W1[(kb + j) * 64 + lane];
            #pragma unroll
            for (int j = 0; j < 8; j++) {
                #pragma unroll
                for (int r = 0; r < 8; r++)
                    acc[r] = fmaf(rl_f(xr[r], kb + j), wb[j], acc[r]);
            }
        }
        #pragma unroll
        for (int r = 0; r < 8; r++)
            P[(size_t)(base + r) * 64 + lane] = f2bf(acc[r]);
    }
}

// ---------------- per-bucket: degrees -> dinv/dinv2 + LDS-staged csr + P pre-scale ----------------
// r10 rework of the serial-chain pole: (1) 1024 threads/block (was 256; 392 blocks = 1.5
// blocks/CU, so per-block parallelism IS machine parallelism); (2) binned chunk staged in
// LDS once — histogram and fill both read LDS (deletes the 6.4MB global re-read);
// (3) csr built in LDS via local cursors then flushed COALESCED (was 1.6M scattered 4B
// global writes, each dirtying a 128B line). LDS: 18.4K bin_s + 18.4K cs_s + h/ts/sdv ~40KB.
__global__ __launch_bounds__(1024) void k_bcsr(const int* __restrict__ binned, const int* __restrict__ bcur,
                                               float* __restrict__ dinv, float* __restrict__ dinv2,
                                               int* __restrict__ csr, unsigned short* __restrict__ P) {
    __shared__ int bin_s[CAP];
    __shared__ int cs_s[CAP];
    __shared__ int h[NPB];
    __shared__ int ts[NPB];
    __shared__ float sdv[NPB];
    int t = threadIdx.x;
    int b = blockIdx.x;
    int nb0  = b << 8;
    int ebeg = b * CAP;
    int ecnt = bcur[b]; if (ecnt > CAP) ecnt = CAP;
    if (t < NPB) h[t] = 0;
    __syncthreads();
    // stage binned -> LDS (coalesced) + histogram from LDS
    for (int i = t; i < ecnt; i += 1024) {
        int p = binned[ebeg + i];
        bin_s[i] = p;
        atomicAdd(&h[p >> 17], 1);
    }
    __syncthreads();
    int c = 0;
    if (t < NPB) { c = h[t]; ts[t] = c; }
    __syncthreads();
    for (int o = 1; o < NPB; o <<= 1) {
        int v = (t >= o && t < NPB) ? ts[t - o] : 0;
        __syncthreads();
        if (t >= o && t < NPB) ts[t] += v;
        __syncthreads();
    }
    if (t < NPB) {
        int n = nb0 + t;
        float dval = 0.f;
        if (n < N_NODES) {
            float inv = 1.0f / (float)(c + 1);     // +1 self loop
            dinv2[n] = inv;
            dval     = sqrtf(inv);
            dinv[n]  = dval;
        }
        sdv[t] = dval;
        h[t] = ts[t] - c;                          // local write cursor (0-based in bucket)
    }
    __syncthreads();
    // node-sorted fill into LDS
    for (int i = t; i < ecnt; i += 1024) {
        int p = bin_s[i];
        int q = atomicAdd(&h[p >> 17], 1);
        cs_s[q] = p;                               // keep src | dstLow<<17
    }
    __syncthreads();
    // coalesced flush to global csr
    for (int i = t; i < ecnt; i += 1024)
        csr[ebeg + i] = cs_s[i];
    // ---- scale this bucket's P rows by dinv (8 uint4 = 64 bf16 per row) ----
    for (int i = t; i < NPB * 8; i += 1024) {
        int row = i >> 3;
        int nn  = nb0 + row;
        if (nn >= N_NODES) break;                  // row monotone in i per thread
        float dv = sdv[row];
        uint4* pp = (uint4*)P + (size_t)nn * 8 + (i & 7);
        uint4 v = *pp;
        v.x = scale2(v.x, dv); v.y = scale2(v.y, dv);
        v.z = scale2(v.z, dv); v.w = scale2(v.w, dv);
        *pp = v;
    }
}

// ---------------- GEMM layers 2/3 ----------------
// P holds SCALED H (Hprev * dinv[n], bf16).
// xin = relu(E[n] + bprev + Pscaled[n]*dinv[n]);  (== E + b + Hprev*dinv2)
// Hnew = xin @ W; store P = f2bf(Hnew * dinv[n])  (scaled for the next aggregation)
// POOLI (layer 3): pool[batch[n]] += bcurr + Hnew[n]*dinv2[n]  (uses unscaled register acc)
template<bool POOLI>
__global__ __launch_bounds__(256) void k_gemm(const float* __restrict__ E,
                                              unsigned short* P,            // aliased in/out (row-private)
                                              const float* __restrict__ W,
                                              const float* __restrict__ bprev,
                                              const float* __restrict__ bcurr,
                                              const float* __restrict__ dinv,
                                              const float* __restrict__ dinv2,
                                              const int* __restrict__ batch,
                                              float* __restrict__ pool) {
    int lane = threadIdx.x & 63;
    int wv   = threadIdx.x >> 6;
    int base = blockIdx.x * 32 + wv * 8;           // grid exact (3125*32)
    float bp = bprev[lane];
    float xr[8], acc[8], dn[8];
    #pragma unroll
    for (int r = 0; r < 8; r++) dn[r] = dinv[base + r];
    #pragma unroll
    for (int r = 0; r < 8; r++) {
        int n = base + r;
        float hp = bf2f(P[(size_t)n * 64 + lane]); // scaled Hprev
        float a  = E[(size_t)n * 64 + lane] + fmaf(hp, dn[r], bp);
        xr[r]  = fmaxf(a, 0.f);
        acc[r] = 0.f;
    }
    for (int kb = 0; kb < 64; kb += 8) {
        float wb[8];
        #pragma unroll
        for (int j = 0; j < 8; j++) wb[j] = W[(kb + j) * 64 + lane];
        #pragma unroll
        for (int j = 0; j < 8; j++) {
            #pragma unroll
            for (int r = 0; r < 8; r++)
                acc[r] = fmaf(rl_f(xr[r], kb + j), wb[j], acc[r]);
        }
    }
    #pragma unroll
    for (int r = 0; r < 8; r++)
        P[(size_t)(base + r) * 64 + lane] = f2bf(acc[r] * dn[r]);   // store scaled
    if (POOLI) {
        float bv = bcurr[lane];
        float d2[8];
        #pragma unroll
        for (int r = 0; r < 8; r++) d2[r] = dinv2[base + r];
        int g0 = batch[base], g7 = batch[base + 7];
        if (g0 == g7) {
            float s = 0.f;
            #pragma unroll
            for (int r = 0; r < 8; r++) s += fmaf(acc[r], d2[r], bv);
            atomicAdd(&pool[g0 * 64 + lane], s);
        } else {
            #pragma unroll
            for (int r = 0; r < 8; r++) {
                int g = batch[base + r];
                atomicAdd(&pool[g * 64 + lane], fmaf(acc[r], d2[r], bv));
            }
        }
    }
}

// ---------------- Edge-parallel aggregation (bf16 gather; pre-scaled H, scalar run mask) ----------------
// Wave owns 64 csr slots (node-sorted runs within one bucket).
// Out[dst] += dinv[dst] * sum(Pscaled[src])   (atomic; Out pre-zeroed)
// Proven r9 form: no per-edge coefficient (H pre-scaled by dinv[src]); run boundaries via
// one ballot per window -> SALU bit-test per edge; memory-op sequence identical to r0.
// POOLEP: flush into pool[batch[dst]] instead (layer 3).
// ZROLE: trailing NZB2 blocks zero the pool|E2 span (rides agge1's latency shadow).
template<bool POOLEP, bool ZROLE>
__global__ __launch_bounds__(256, 8) void k_agge(const unsigned short* __restrict__ Hbuf,
                                                 const int* __restrict__ csr,
                                                 const int* __restrict__ bcur,
                                                 const float* __restrict__ dinv,
                                                 const int* __restrict__ batch,
                                                 float* __restrict__ Out,
                                                 float* __restrict__ zbase) {
    int t = threadIdx.x;
    if (ZROLE && blockIdx.x >= AGGE_GRID) {
        float4 z = make_float4(0.f, 0.f, 0.f, 0.f);
        float4* zp = (float4*)zbase;
        int zb = blockIdx.x - AGGE_GRID;
        for (long i = (long)zb * 256 + t; i < (long)ZLEN4_A; i += (long)NZB2 * 256)
            zp[i] = z;
        return;
    }
    int wv   = t >> 6;
    int lane = t & 63;
    int wid  = blockIdx.x * 4 + wv;                // 0 .. SB*WPB-1
    int b    = wid / WPB;
    int lw   = wid - b * WPB;
    int used = bcur[b]; if (used > CAP) used = CAP;
    int e0   = lw * 64;
    int rem  = used - e0;
    if (rem <= 0) return;
    if (rem > 64) rem = 64;
    int base = b * CAP + e0;

    int p = 0;
    if (lane < rem) p = csr[base + lane];          // coalesced 256B (only load in init)
    int sv = p & 0x1FFFF;
    int dv = p >> 17;                              // dstLow (8b)

    // wave-uniform run-start mask (bit i: slot i starts a new dst run); bit 0 cleared
    int dvp = __shfl_up(dv, 1);
    unsigned long long m0 = __ballot(dv != dvp);
    unsigned mlo = __builtin_amdgcn_readfirstlane((unsigned)m0);
    unsigned mhi = __builtin_amdgcn_readfirstlane((unsigned)(m0 >> 32));
    unsigned long long mask = ((((unsigned long long)mhi) << 32) | mlo) & ~1ull;

    auto flush1 = [&](int dl, float a) {
        int dst = (b << 8) + dl;
        if (dst < N_NODES) {
            float val = dinv[dst] * a;             // uniform load
            if (POOLEP) {
                int g = batch[dst];                // uniform load
                atomicAdd(&Out[g * 64 + lane], val);
            } else {
                atomicAdd(&Out[(size_t)dst * 64 + lane], val);
            }
        }
    };

    int cur = rl_i(dv, 0);
    float acc = 0.f;
    int j = 0;
    for (; j + 16 <= rem; j += 16) {
        unsigned short u[16];
        #pragma unroll
        for (int i = 0; i < 16; i++) {             // 16 gathers issued up front (r0 form)
            int s = rl_i(sv, j + i);
            u[i] = Hbuf[(size_t)s * 64 + lane];
        }
        #pragma unroll
        for (int i = 0; i < 16; i++) {
            if ((mask >> (j + i)) & 1) {           // scalar bit-test + scalar branch
                flush1(cur, acc); acc = 0.f; cur = rl_i(dv, j + i);
            }
            acc += bf2f(u[i]);                     // 2 VALU/edge
        }
    }
    for (; j < rem; j++) {
        int s0 = rl_i(sv, j);
        unsigned short u0 = Hbuf[(size_t)s0 * 64 + lane];
        if ((mask >> j) & 1) { flush1(cur, acc); acc = 0.f; cur = rl_i(dv, j); }
        acc += bf2f(u0);
    }
    flush1(cur, acc);
}

// ---------------- mean + classifier ----------------
__device__ __forceinline__ int lbound(const int* __restrict__ a, int n, int v) {
    int lo = 0, hi = n;
    while (lo < hi) { int m = (lo + hi) >> 1; if (a[m] < v) lo = m + 1; else hi = m; }
    return lo;
}

__global__ __launch_bounds__(64) void k_cls(const float* __restrict__ pool, const int* __restrict__ batch,
                                            const float* __restrict__ Wl, const float* __restrict__ bl,
                                            float* __restrict__ out) {
    __shared__ float pm[64];
    __shared__ int bounds[2];
    int g = blockIdx.x;
    int t = threadIdx.x;
    if (t < 2) bounds[t] = lbound(batch, N_NODES, g + t);
    __syncthreads();
    float cnt = (float)(bounds[1] - bounds[0]);
    pm[t] = pool[g * 64 + t] / fmaxf(cnt, 1.0f);
    __syncthreads();
    if (t < N_CLASSES) {
        float o = bl[t];
        #pragma unroll
        for (int k = 0; k < HID; k++) o = fmaf(pm[k], Wl[k * N_CLASSES + t], o);
        out[g * N_CLASSES + t] = o;
    }
}

// ---------------- launch ----------------

extern "C" void kernel_launch(void* const* d_in, const int* in_sizes, int n_in,
                              void* d_out, int out_size, void* d_ws, size_t ws_size,
                              hipStream_t stream) {
    const float* x     = (const float*)d_in[0];
    const int*   eidx  = (const int*)  d_in[1];
    const int*   batch = (const int*)  d_in[2];
    const float* W1 = (const float*)d_in[3];
    const float* b1 = (const float*)d_in[4];
    const float* W2 = (const float*)d_in[5];
    const float* b2 = (const float*)d_in[6];
    const float* W3 = (const float*)d_in[7];
    const float* b3 = (const float*)d_in[8];
    const float* Wl = (const float*)d_in[9];
    const float* bl = (const float*)d_in[10];
    const int* src = eidx;
    const int* dst = eidx + N_EDGES;

    char* p = (char*)d_ws;
    auto alloc = [&](size_t bytes) -> void* {
        void* r = (void*)p;
        p += (bytes + 255) & ~(size_t)255;
        return r;
    };
    float* dinv  = (float*)alloc((size_t)N_NODES * 4);
    float* dinv2 = (float*)alloc((size_t)N_NODES * 4);
    int*   csr   = (int*)  alloc((size_t)SB * CAP * 4);
    unsigned short* P = (unsigned short*)alloc((size_t)N_NODES * 64 * 2);  // bf16 H (scaled)
    float* E1    = (float*)alloc((size_t)N_NODES * 64 * 4);   // edge sums L1
    float* pool  = (float*)alloc((size_t)N_GRAPHS * 64 * 4);  // contiguous after E1
    float* E2    = (float*)alloc((size_t)N_NODES * 64 * 4);   // contiguous after pool
    int*   bcur  = (int*)  alloc((size_t)SB * 4);
    int*   binned = (int*) alloc((size_t)SB * CAP * 4);

    const int front_grid = NCHUNK + NZB + GEMM_GRID;

    // ---- front: scatter | zero(E1) | gemm1 (all independent) ----
    hipMemsetAsync(bcur, 0, (size_t)SB * 4, stream);
    k_front<<<front_grid, 256, 0, stream>>>(src, dst, bcur, binned, x, W1, P, E1);
    // bcsr: degrees + LDS-staged csr fill + in-place scale P1 *= dinv (1024 thr)
    k_bcsr <<<SB, 1024, 0, stream>>>(binned, bcur, dinv, dinv2, csr, P);

    // layer 1 edges: scaled-H1 gathers -> E1 ; trailing blocks zero pool|E2
    k_agge<false, true ><<<AGGE_GRID + NZB2, 256, 0, stream>>>(P, csr, bcur, dinv, batch, E1, pool);
    // layer 2: relu(E1 + b1 + Ps*dinv) @ W2 -> H2 (scaled, in-place in P); edges -> E2
    k_gemm<false><<<GEMM_GRID, 256, 0, stream>>>(E1, P, W2, b1, nullptr, dinv, dinv2, batch, nullptr);
    k_agge<false, false><<<AGGE_GRID, 256, 0, stream>>>(P, csr, bcur, dinv, batch, E2, nullptr);
    // layer 3: relu(E2 + b2 + Ps*dinv) @ W3 -> H3; self terms -> pool; edges -> pool
    k_gemm<true ><<<GEMM_GRID, 256, 0, stream>>>(E2, P, W3, b2, b3, dinv, dinv2, batch, pool);
    k_agge<true , false><<<AGGE_GRID, 256, 0, stream>>>(P, csr, bcur, dinv, batch, pool, nullptr);

    // mean + classifier
    k_cls<<<N_GRAPHS, 64, 0, stream>>>(pool, batch, Wl, bl, (float*)d_out);
}

// Round 11
// 311.648 us; speedup vs baseline: 1.7709x; 1.1402x over previous
//
#include <hip/hip_runtime.h>
#include <hip/hip_bf16.h>

#define N_NODES   100000
#define N_EDGES   1600000
#define F_IN      64
#define HID       64
#define N_CLASSES 45
#define N_GRAPHS  256
#define SB        392         // super-buckets: bucket = dst >> 8 (0..390)
#define NPB       256         // nodes per bucket
#define CAP       4608        // fixed bucket capacity; 4608 = 72*64 (mean 4082, sigma 64 -> +8s)
#define WPB       72          // waves per bucket in k_agge (CAP/64)
#define CHUNK     4096        // edges per scatter workgroup
#define NCHUNK    391         // ceil(N_EDGES / CHUNK)
#define NZB       192         // zero-blocks in the front kernel (E1 only)
#define GEMM_GRID 782         // ceil(N_NODES / 128) MFMA gemm blocks
#define AGGE_GRID 7056        // SB*WPB/4
#define NZB2      192         // zero-role blocks appended to agge1 (pool+E2)
#define ZLEN4_F   1600000     // E1 bytes/16  (25.6 MB)
#define ZLEN4_A   1604096     // (pool 64KB + E2 25.6MB)/16
#define LW        72          // LDS row stride in bf16 elems (64+8 -> 144B, 2-way-conflict free)

typedef __attribute__((ext_vector_type(8))) short bf16x8;
typedef __attribute__((ext_vector_type(4))) float f32x4;
union B128 { uint4 u; bf16x8 b; };

__device__ __forceinline__ float rl_f(float v, int k) {
    return __uint_as_float(__builtin_amdgcn_readlane(__float_as_uint(v), k));
}
__device__ __forceinline__ int rl_i(int v, int k) {
    return __builtin_amdgcn_readlane(v, k);
}
// fp32 <-> bf16 (RNE)
__device__ __forceinline__ unsigned short f2bf(float x) {
    unsigned u = __float_as_uint(x);
    unsigned r = u + 0x7FFFu + ((u >> 16) & 1u);
    return (unsigned short)(r >> 16);
}
__device__ __forceinline__ float bf2f(unsigned short h) {
    return __uint_as_float(((unsigned)h) << 16);
}
// scale a packed bf16 pair by dv (unpack-mul-repack)
__device__ __forceinline__ unsigned scale2(unsigned u, float dv) {
    float lo = __uint_as_float(u << 16) * dv;
    float hi = __uint_as_float(u & 0xFFFF0000u) * dv;
    return (((unsigned)f2bf(hi)) << 16) | (unsigned)f2bf(lo);
}

// ---------------- W transpose+convert: Wt[l][c*64+k] = bf16(W_l[k][c]) ----------------
__global__ __launch_bounds__(256) void k_prep(const float* __restrict__ W1, const float* __restrict__ W2,
                                              const float* __restrict__ W3, unsigned short* __restrict__ Wt) {
    const float* W = (blockIdx.x == 0) ? W1 : (blockIdx.x == 1) ? W2 : W3;
    unsigned short* o = Wt + blockIdx.x * 4096;
    int t = threadIdx.x;
    #pragma unroll
    for (int i = 0; i < 16; i++) {
        int e = i * 256 + t;                       // c = e>>6, k = e&63
        o[e] = f2bf(W[(e & 63) * 64 + (e >> 6)]);
    }
}

// ---------------- front kernel: scatter | zero(E1) | gemm1 (MFMA) ----------------
// payload: src(17b) | dstLow(8b)<<17
__global__ __launch_bounds__(256) void k_front(const int* __restrict__ src, const int* __restrict__ dst,
                                               int* __restrict__ bcur, int* __restrict__ binned,
                                               const float* __restrict__ x, const unsigned short* __restrict__ Wt1,
                                               unsigned short* __restrict__ P, float* __restrict__ zbase) {
    int bid = blockIdx.x;
    int t   = threadIdx.x;
    if (bid < NCHUNK) {
        // ---- scatter (bucket multisplit) ----
        __shared__ int stg[CHUNK];
        __shared__ unsigned short bkt[CHUNK];
        __shared__ int h[512], cur[512], off[512];
        __shared__ int ps[256];
        h[t] = 0; h[t + 256] = 0;
        __syncthreads();
        int base4 = bid * (CHUNK / 4);
        // phase 1: histogram (dst read #1)
        #pragma unroll
        for (int i = 0; i < CHUNK / 1024; i++) {
            int e4 = base4 + i * 256 + t;
            if (e4 < N_EDGES / 4) {
                int4 d = ((const int4*)dst)[e4];
                atomicAdd(&h[d.x >> 8], 1);
                atomicAdd(&h[d.y >> 8], 1);
                atomicAdd(&h[d.z >> 8], 1);
                atomicAdd(&h[d.w >> 8], 1);
            }
        }
        __syncthreads();
        // phase 2: pair-scan over 512 slots + global reservation; off = gbase - lbase
        int a0 = h[2 * t], a1 = h[2 * t + 1];
        ps[t] = a0 + a1;
        __syncthreads();
        for (int o = 1; o < 256; o <<= 1) {
            int v = (t >= o) ? ps[t - o] : 0;
            __syncthreads();
            if (t >= o) ps[t] += v;
            __syncthreads();
        }
        int pex = ps[t] - (a0 + a1);               // exclusive over pairs
        int e0 = pex, e1 = pex + a0;
        cur[2 * t] = e0; cur[2 * t + 1] = e1;
        if (2 * t < SB && a0 > 0)
            off[2 * t] = (2 * t) * CAP + atomicAdd(&bcur[2 * t], a0) - e0;
        if (2 * t + 1 < SB && a1 > 0)
            off[2 * t + 1] = (2 * t + 1) * CAP + atomicAdd(&bcur[2 * t + 1], a1) - e1;
        __syncthreads();
        int total = ps[255];                        // edges in this chunk
        // phase 3: re-read dst (+src), stage payload + bucket id
        #pragma unroll
        for (int i = 0; i < CHUNK / 1024; i++) {
            int e4 = base4 + i * 256 + t;
            if (e4 < N_EDGES / 4) {
                int4 d  = ((const int4*)dst)[e4];   // L2-hot re-read
                int4 s4 = ((const int4*)src)[e4];
                int q;
                q = atomicAdd(&cur[d.x >> 8], 1); stg[q] = s4.x | ((d.x & 255) << 17); bkt[q] = (unsigned short)(d.x >> 8);
                q = atomicAdd(&cur[d.y >> 8], 1); stg[q] = s4.y | ((d.y & 255) << 17); bkt[q] = (unsigned short)(d.y >> 8);
                q = atomicAdd(&cur[d.z >> 8], 1); stg[q] = s4.z | ((d.z & 255) << 17); bkt[q] = (unsigned short)(d.z >> 8);
                q = atomicAdd(&cur[d.w >> 8], 1); stg[q] = s4.w | ((d.w & 255) << 17); bkt[q] = (unsigned short)(d.w >> 8);
            }
        }
        __syncthreads();
        // phase 4: flat flush — coalesced LDS read, run-coalesced global write
        for (int i = t; i < total; i += 256) {
            int b = bkt[i];
            binned[off[b] + i] = stg[i];
        }
    } else if (bid < NCHUNK + NZB) {
        // ---- zero E1 ----
        float4 z = make_float4(0.f, 0.f, 0.f, 0.f);
        float4* zp = (float4*)zbase;
        int zb = bid - NCHUNK;
        for (long i = (long)zb * 256 + t; i < (long)ZLEN4_F; i += (long)NZB * 256)
            zp[i] = z;
    } else {
        // ---- gemm1 (MFMA): P = bf16(x @ W1), unscaled (k_bcsr scales by dinv later) ----
        __shared__ unsigned short xin_s[128 * LW];
        __shared__ unsigned short wt_s[64 * LW];
        int nb = (bid - NCHUNK - NZB) * 128;
        #pragma unroll
        for (int i = 0; i < 16; i++) {             // stage Wt1 -> LDS
            int e = i * 256 + t;
            wt_s[(e >> 6) * LW + (e & 63)] = Wt1[e];
        }
        #pragma unroll
        for (int i = 0; i < 8; i++) {              // stage x rows (bf16) -> LDS
            int f = i * 256 + t;
            int row = f >> 4, q = f & 15;
            int gR = nb + row;
            unsigned u0 = 0, u1 = 0;
            if (gR < N_NODES) {
                float4 xv = ((const float4*)x)[(size_t)gR * 16 + q];
                u0 = ((unsigned)f2bf(xv.y) << 16) | f2bf(xv.x);
                u1 = ((unsigned)f2bf(xv.w) << 16) | f2bf(xv.z);
            }
            *(uint2*)&xin_s[row * LW + q * 4] = make_uint2(u0, u1);
        }
        __syncthreads();
        int lane = t & 63, w = t >> 6;
        int l15 = lane & 15, l4 = lane >> 4;
        B128 bfr[4][2];
        #pragma unroll
        for (int nt = 0; nt < 4; nt++)
            #pragma unroll
            for (int ks = 0; ks < 2; ks++)
                bfr[nt][ks].u = *(const uint4*)&wt_s[(nt * 16 + l15) * LW + ks * 32 + l4 * 8];
        f32x4 acc[2][4] = {};
        #pragma unroll
        for (int m = 0; m < 2; m++) {
            int rb = w * 32 + m * 16;
            B128 a0, a1;
            a0.u = *(const uint4*)&xin_s[(rb + l15) * LW +  0 + l4 * 8];
            a1.u = *(const uint4*)&xin_s[(rb + l15) * LW + 32 + l4 * 8];
            #pragma unroll
            for (int nt = 0; nt < 4; nt++) {
                acc[m][nt] = __builtin_amdgcn_mfma_f32_16x16x32_bf16(a0.b, bfr[nt][0].b, acc[m][nt], 0, 0, 0);
                acc[m][nt] = __builtin_amdgcn_mfma_f32_16x16x32_bf16(a1.b, bfr[nt][1].b, acc[m][nt], 0, 0, 0);
            }
        }
        #pragma unroll
        for (int m = 0; m < 2; m++) {
            int Rbase = nb + w * 32 + m * 16;
            #pragma unroll
            for (int nt = 0; nt < 4; nt++)
                #pragma unroll
                for (int r = 0; r < 4; r++) {
                    int row = Rbase + l4 * 4 + r;   // C layout: col=lane&15, row=(lane>>4)*4+reg [m89]
                    if (row < N_NODES)
                        P[(size_t)row * 64 + nt * 16 + l15] = f2bf(acc[m][nt][r]);
                }
        }
    }
}

// ---------------- per-bucket: degrees -> dinv/dinv2 + LDS-staged csr + P pre-scale ----------------
// (proven r10 form: 1024 thr, binned staged once in LDS, csr built in LDS then flushed coalesced)
__global__ __launch_bounds__(1024) void k_bcsr(const int* __restrict__ binned, const int* __restrict__ bcur,
                                               float* __restrict__ dinv, float* __restrict__ dinv2,
                                               int* __restrict__ csr, unsigned short* __restrict__ P) {
    __shared__ int bin_s[CAP];
    __shared__ int cs_s[CAP];
    __shared__ int h[NPB];
    __shared__ int ts[NPB];
    __shared__ float sdv[NPB];
    int t = threadIdx.x;
    int b = blockIdx.x;
    int nb0  = b << 8;
    int ebeg = b * CAP;
    int ecnt = bcur[b]; if (ecnt > CAP) ecnt = CAP;
    if (t < NPB) h[t] = 0;
    __syncthreads();
    for (int i = t; i < ecnt; i += 1024) {
        int p = binned[ebeg + i];
        bin_s[i] = p;
        atomicAdd(&h[p >> 17], 1);
    }
    __syncthreads();
    int c = 0;
    if (t < NPB) { c = h[t]; ts[t] = c; }
    __syncthreads();
    for (int o = 1; o < NPB; o <<= 1) {
        int v = (t >= o && t < NPB) ? ts[t - o] : 0;
        __syncthreads();
        if (t >= o && t < NPB) ts[t] += v;
        __syncthreads();
    }
    if (t < NPB) {
        int n = nb0 + t;
        float dval = 0.f;
        if (n < N_NODES) {
            float inv = 1.0f / (float)(c + 1);     // +1 self loop
            dinv2[n] = inv;
            dval     = sqrtf(inv);
            dinv[n]  = dval;
        }
        sdv[t] = dval;
        h[t] = ts[t] - c;                          // local write cursor (0-based in bucket)
    }
    __syncthreads();
    for (int i = t; i < ecnt; i += 1024) {
        int p = bin_s[i];
        int q = atomicAdd(&h[p >> 17], 1);
        cs_s[q] = p;                               // keep src | dstLow<<17
    }
    __syncthreads();
    for (int i = t; i < ecnt; i += 1024)
        csr[ebeg + i] = cs_s[i];
    // ---- scale this bucket's P rows by dinv (8 uint4 = 64 bf16 per row) ----
    for (int i = t; i < NPB * 8; i += 1024) {
        int row = i >> 3;
        int nn  = nb0 + row;
        if (nn >= N_NODES) break;                  // row monotone in i per thread
        float dv = sdv[row];
        uint4* pp = (uint4*)P + (size_t)nn * 8 + (i & 7);
        uint4 v = *pp;
        v.x = scale2(v.x, dv); v.y = scale2(v.y, dv);
        v.z = scale2(v.z, dv); v.w = scale2(v.w, dv);
        *pp = v;
    }
}

// ---------------- GEMM layers 2/3 (MFMA) ----------------
// P holds SCALED H (Hprev * dinv[n], bf16).
// xin = relu(E[n] + bprev + Pscaled[n]*dinv[n])  (== E + b + Hprev*dinv2), bf16 -> LDS
// acc = xin @ W (mfma 16x16x32); store P = f2bf(acc * dinv[n]) (scaled for next agge)
// POOLI (layer 3): pool[batch[n]] += bcurr + acc*dinv2[n]; per 16-row tile, cross-lane
// reduce (2x shfl_xor) then ONE 16-lane atomic when the tile is graph-uniform (common);
// per-row fallback at graph boundaries / tail.
template<bool POOLI>
__global__ __launch_bounds__(256) void k_gemm(const float* __restrict__ E,
                                              unsigned short* P,            // aliased in/out (row-private)
                                              const unsigned short* __restrict__ Wt,
                                              const float* __restrict__ bprev,
                                              const float* __restrict__ bcurr,
                                              const float* __restrict__ dinv,
                                              const float* __restrict__ dinv2,
                                              const int* __restrict__ batch,
                                              float* __restrict__ pool) {
    __shared__ unsigned short xin_s[128 * LW];
    __shared__ unsigned short wt_s[64 * LW];
    int t  = threadIdx.x;
    int nb = blockIdx.x * 128;
    #pragma unroll
    for (int i = 0; i < 16; i++) {                 // stage Wt -> LDS
        int e = i * 256 + t;
        wt_s[(e >> 6) * LW + (e & 63)] = Wt[e];
    }
    #pragma unroll
    for (int i = 0; i < 8; i++) {                  // stage xin rows (bf16) -> LDS
        int f = i * 256 + t;
        int row = f >> 4, q = f & 15;
        int gR = nb + row;
        unsigned u0 = 0, u1 = 0;
        if (gR < N_NODES) {
            float4  ev = ((const float4*)E)[(size_t)gR * 16 + q];
            ushort4 pv = ((const ushort4*)P)[(size_t)gR * 16 + q];
            float dn = dinv[gR];
            float4 bp = ((const float4*)bprev)[q];
            float x0 = fmaxf(ev.x + fmaf(bf2f(pv.x), dn, bp.x), 0.f);
            float x1 = fmaxf(ev.y + fmaf(bf2f(pv.y), dn, bp.y), 0.f);
            float x2 = fmaxf(ev.z + fmaf(bf2f(pv.z), dn, bp.z), 0.f);
            float x3 = fmaxf(ev.w + fmaf(bf2f(pv.w), dn, bp.w), 0.f);
            u0 = ((unsigned)f2bf(x1) << 16) | f2bf(x0);
            u1 = ((unsigned)f2bf(x3) << 16) | f2bf(x2);
        }
        *(uint2*)&xin_s[row * LW + q * 4] = make_uint2(u0, u1);
    }
    __syncthreads();
    int lane = t & 63, w = t >> 6;
    int l15 = lane & 15, l4 = lane >> 4;
    B128 bfr[4][2];
    #pragma unroll
    for (int nt = 0; nt < 4; nt++)
        #pragma unroll
        for (int ks = 0; ks < 2; ks++)
            bfr[nt][ks].u = *(const uint4*)&wt_s[(nt * 16 + l15) * LW + ks * 32 + l4 * 8];
    f32x4 acc[2][4] = {};
    #pragma unroll
    for (int m = 0; m < 2; m++) {
        int rb = w * 32 + m * 16;
        B128 a0, a1;
        a0.u = *(const uint4*)&xin_s[(rb + l15) * LW +  0 + l4 * 8];
        a1.u = *(const uint4*)&xin_s[(rb + l15) * LW + 32 + l4 * 8];
        #pragma unroll
        for (int nt = 0; nt < 4; nt++) {
            acc[m][nt] = __builtin_amdgcn_mfma_f32_16x16x32_bf16(a0.b, bfr[nt][0].b, acc[m][nt], 0, 0, 0);
            acc[m][nt] = __builtin_amdgcn_mfma_f32_16x16x32_bf16(a1.b, bfr[nt][1].b, acc[m][nt], 0, 0, 0);
        }
    }
    #pragma unroll
    for (int m = 0; m < 2; m++) {
        int Rbase = nb + w * 32 + m * 16;
        float dnr[4], d2r[4];
        #pragma unroll
        for (int r = 0; r < 4; r++) {
            int row = Rbase + l4 * 4 + r;
            bool v = row < N_NODES;
            dnr[r] = v ? dinv[row] : 0.f;
            d2r[r] = (POOLI && v) ? dinv2[row] : 0.f;
        }
        #pragma unroll
        for (int nt = 0; nt < 4; nt++)
            #pragma unroll
            for (int r = 0; r < 4; r++) {
                int row = Rbase + l4 * 4 + r;       // C layout: col=lane&15, row=(lane>>4)*4+reg [m89]
                if (row < N_NODES)
                    P[(size_t)row * 64 + nt * 16 + l15] = f2bf(acc[m][nt][r] * dnr[r]);
            }
        if (POOLI) {
            bool full = (Rbase + 15) < N_NODES;
            int g0 = -1, g15 = -2;
            if (full) { g0 = batch[Rbase]; g15 = batch[Rbase + 15]; }
            if (full && g0 == g15) {
                #pragma unroll
                for (int nt = 0; nt < 4; nt++) {
                    float v = 0.f;
                    #pragma unroll
                    for (int r = 0; r < 4; r++) v = fmaf(acc[m][nt][r], d2r[r], v);
                    v += __shfl_xor(v, 16);
                    v += __shfl_xor(v, 32);
                    if (lane < 16)
                        atomicAdd(&pool[g0 * 64 + nt * 16 + lane], fmaf(16.f, bcurr[nt * 16 + lane], v));
                }
            } else if (Rbase < N_NODES) {
                #pragma unroll
                for (int nt = 0; nt < 4; nt++) {
                    float bc = bcurr[nt * 16 + l15];
                    #pragma unroll
                    for (int r = 0; r < 4; r++) {
                        int row = Rbase + l4 * 4 + r;
                        if (row < N_NODES)
                            atomicAdd(&pool[batch[row] * 64 + nt * 16 + l15], fmaf(acc[m][nt][r], d2r[r], bc));
                    }
                }
            }
        }
    }
}

// ---------------- Edge-parallel aggregation (bf16 gather; pre-scaled H, scalar run mask) ----------------
// (proven r9/r10 form, byte-identical)
template<bool POOLEP, bool ZROLE>
__global__ __launch_bounds__(256, 8) void k_agge(const unsigned short* __restrict__ Hbuf,
                                                 const int* __restrict__ csr,
                                                 const int* __restrict__ bcur,
                                                 const float* __restrict__ dinv,
                                                 const int* __restrict__ batch,
                                                 float* __restrict__ Out,
                                                 float* __restrict__ zbase) {
    int t = threadIdx.x;
    if (ZROLE && blockIdx.x >= AGGE_GRID) {
        float4 z = make_float4(0.f, 0.f, 0.f, 0.f);
        float4* zp = (float4*)zbase;
        int zb = blockIdx.x - AGGE_GRID;
        for (long i = (long)zb * 256 + t; i < (long)ZLEN4_A; i += (long)NZB2 * 256)
            zp[i] = z;
        return;
    }
    int wv   = t >> 6;
    int lane = t & 63;
    int wid  = blockIdx.x * 4 + wv;                // 0 .. SB*WPB-1
    int b    = wid / WPB;
    int lw   = wid - b * WPB;
    int used = bcur[b]; if (used > CAP) used = CAP;
    int e0   = lw * 64;
    int rem  = used - e0;
    if (rem <= 0) return;
    if (rem > 64) rem = 64;
    int base = b * CAP + e0;

    int p = 0;
    if (lane < rem) p = csr[base + lane];          // coalesced 256B (only load in init)
    int sv = p & 0x1FFFF;
    int dv = p >> 17;                              // dstLow (8b)

    // wave-uniform run-start mask (bit i: slot i starts a new dst run); bit 0 cleared
    int dvp = __shfl_up(dv, 1);
    unsigned long long m0 = __ballot(dv != dvp);
    unsigned mlo = __builtin_amdgcn_readfirstlane((unsigned)m0);
    unsigned mhi = __builtin_amdgcn_readfirstlane((unsigned)(m0 >> 32));
    unsigned long long mask = ((((unsigned long long)mhi) << 32) | mlo) & ~1ull;

    auto flush1 = [&](int dl, float a) {
        int dst = (b << 8) + dl;
        if (dst < N_NODES) {
            float val = dinv[dst] * a;             // uniform load
            if (POOLEP) {
                int g = batch[dst];                // uniform load
                atomicAdd(&Out[g * 64 + lane], val);
            } else {
                atomicAdd(&Out[(size_t)dst * 64 + lane], val);
            }
        }
    };

    int cur = rl_i(dv, 0);
    float acc = 0.f;
    int j = 0;
    for (; j + 16 <= rem; j += 16) {
        unsigned short u[16];
        #pragma unroll
        for (int i = 0; i < 16; i++) {             // 16 gathers issued up front (r0 form)
            int s = rl_i(sv, j + i);
            u[i] = Hbuf[(size_t)s * 64 + lane];
        }
        #pragma unroll
        for (int i = 0; i < 16; i++) {
            if ((mask >> (j + i)) & 1) {           // scalar bit-test + scalar branch
                flush1(cur, acc); acc = 0.f; cur = rl_i(dv, j + i);
            }
            acc += bf2f(u[i]);                     // 2 VALU/edge
        }
    }
    for (; j < rem; j++) {
        int s0 = rl_i(sv, j);
        unsigned short u0 = Hbuf[(size_t)s0 * 64 + lane];
        if ((mask >> j) & 1) { flush1(cur, acc); acc = 0.f; cur = rl_i(dv, j); }
        acc += bf2f(u0);
    }
    flush1(cur, acc);
}

// ---------------- mean + classifier ----------------
__device__ __forceinline__ int lbound(const int* __restrict__ a, int n, int v) {
    int lo = 0, hi = n;
    while (lo < hi) { int m = (lo + hi) >> 1; if (a[m] < v) lo = m + 1; else hi = m; }
    return lo;
}

__global__ __launch_bounds__(64) void k_cls(const float* __restrict__ pool, const int* __restrict__ batch,
                                            const float* __restrict__ Wl, const float* __restrict__ bl,
                                            float* __restrict__ out) {
    __shared__ float pm[64];
    __shared__ int bounds[2];
    int g = blockIdx.x;
    int t = threadIdx.x;
    if (t < 2) bounds[t] = lbound(batch, N_NODES, g + t);
    __syncthreads();
    float cnt = (float)(bounds[1] - bounds[0]);
    pm[t] = pool[g * 64 + t] / fmaxf(cnt, 1.0f);
    __syncthreads();
    if (t < N_CLASSES) {
        float o = bl[t];
        #pragma unroll
        for (int k = 0; k < HID; k++) o = fmaf(pm[k], Wl[k * N_CLASSES + t], o);
        out[g * N_CLASSES + t] = o;
    }
}

// ---------------- launch ----------------

extern "C" void kernel_launch(void* const* d_in, const int* in_sizes, int n_in,
                              void* d_out, int out_size, void* d_ws, size_t ws_size,
                              hipStream_t stream) {
    const float* x     = (const float*)d_in[0];
    const int*   eidx  = (const int*)  d_in[1];
    const int*   batch = (const int*)  d_in[2];
    const float* W1 = (const float*)d_in[3];
    const float* b1 = (const float*)d_in[4];
    const float* W2 = (const float*)d_in[5];
    const float* b2 = (const float*)d_in[6];
    const float* W3 = (const float*)d_in[7];
    const float* b3 = (const float*)d_in[8];
    const float* Wl = (const float*)d_in[9];
    const float* bl = (const float*)d_in[10];
    const int* src = eidx;
    const int* dst = eidx + N_EDGES;

    char* p = (char*)d_ws;
    auto alloc = [&](size_t bytes) -> void* {
        void* r = (void*)p;
        p += (bytes + 255) & ~(size_t)255;
        return r;
    };
    float* dinv  = (float*)alloc((size_t)N_NODES * 4);
    float* dinv2 = (float*)alloc((size_t)N_NODES * 4);
    int*   csr   = (int*)  alloc((size_t)SB * CAP * 4);
    unsigned short* P = (unsigned short*)alloc((size_t)N_NODES * 64 * 2);  // bf16 H (scaled)
    float* E1    = (float*)alloc((size_t)N_NODES * 64 * 4);   // edge sums L1
    float* pool  = (float*)alloc((size_t)N_GRAPHS * 64 * 4);  // contiguous after E1
    float* E2    = (float*)alloc((size_t)N_NODES * 64 * 4);   // contiguous after pool
    int*   bcur  = (int*)  alloc((size_t)SB * 4);
    int*   binned = (int*) alloc((size_t)SB * CAP * 4);
    unsigned short* Wt = (unsigned short*)alloc((size_t)3 * 4096 * 2);  // bf16 W^T x3

    const int front_grid = NCHUNK + NZB + GEMM_GRID;

    // ---- prep: W -> bf16 transposed ----
    hipMemsetAsync(bcur, 0, (size_t)SB * 4, stream);
    k_prep<<<3, 256, 0, stream>>>(W1, W2, W3, Wt);
    // ---- front: scatter | zero(E1) | gemm1-MFMA (all independent) ----
    k_front<<<front_grid, 256, 0, stream>>>(src, dst, bcur, binned, x, Wt, P, E1);
    // bcsr: degrees + LDS-staged csr fill + in-place scale P1 *= dinv (1024 thr)
    k_bcsr <<<SB, 1024, 0, stream>>>(binned, bcur, dinv, dinv2, csr, P);

    // layer 1 edges: scaled-H1 gathers -> E1 ; trailing blocks zero pool|E2
    k_agge<false, true ><<<AGGE_GRID + NZB2, 256, 0, stream>>>(P, csr, bcur, dinv, batch, E1, pool);
    // layer 2: relu(E1 + b1 + Ps*dinv) @ W2 -> H2 (scaled, in-place in P); edges -> E2
    k_gemm<false><<<GEMM_GRID, 256, 0, stream>>>(E1, P, Wt + 4096, b1, nullptr, dinv, dinv2, batch, nullptr);
    k_agge<false, false><<<AGGE_GRID, 256, 0, stream>>>(P, csr, bcur, dinv, batch, E2, nullptr);
    // layer 3: relu(E2 + b2 + Ps*dinv) @ W3 -> H3; self terms -> pool; edges -> pool
    k_gemm<true ><<<GEMM_GRID, 256, 0, stream>>>(E2, P, Wt + 8192, b2, b3, dinv, dinv2, batch, pool);
    k_agge<true , false><<<AGGE_GRID, 256, 0, stream>>>(P, csr, bcur, dinv, batch, pool, nullptr);

    // mean + classifier
    k_cls<<<N_GRAPHS, 64, 0, stream>>>(pool, batch, Wl, bl, (float*)d_out);
}

// Round 12
// 309.204 us; speedup vs baseline: 1.7849x; 1.0079x over previous
//
#include <hip/hip_runtime.h>
#include <hip/hip_bf16.h>

#define N_NODES   100000
#define N_EDGES   1600000
#define F_IN      64
#define HID       64
#define N_CLASSES 45
#define N_GRAPHS  256
#define SB        392         // super-buckets: bucket = dst >> 8 (0..390)
#define NPB       256         // nodes per bucket
#define CAP       4608        // fixed bucket capacity; 4608 = 72*64 (mean 4082, sigma 64 -> +8s)
#define WPB       72          // waves per bucket in k_agge (CAP/64)
#define CHUNK     4096        // edges per scatter workgroup
#define NCHUNK    391         // ceil(N_EDGES / CHUNK)
#define NZB       192         // zero-blocks in the front kernel (E1 only)
#define GEMM_GRID 782         // ceil(N_NODES / 128) MFMA gemm blocks
#define AGGE_GRID 7056        // SB*WPB/4
#define NZB2      192         // zero-role blocks appended to agge1 (pool+E2)
#define ZLEN4_F   1600000     // E1 bytes/16  (25.6 MB)
#define ZLEN4_A   1604096     // (pool 64KB + E2 25.6MB)/16
#define LW        72          // LDS row stride in bf16 elems (64+8 -> 144B, 2-way-conflict free)

typedef __attribute__((ext_vector_type(8))) short bf16x8;
typedef __attribute__((ext_vector_type(4))) float f32x4;
union B128 { uint4 u; bf16x8 b; };

__device__ __forceinline__ float rl_f(float v, int k) {
    return __uint_as_float(__builtin_amdgcn_readlane(__float_as_uint(v), k));
}
__device__ __forceinline__ int rl_i(int v, int k) {
    return __builtin_amdgcn_readlane(v, k);
}
// fp32 <-> bf16 (RNE)
__device__ __forceinline__ unsigned short f2bf(float x) {
    unsigned u = __float_as_uint(x);
    unsigned r = u + 0x7FFFu + ((u >> 16) & 1u);
    return (unsigned short)(r >> 16);
}
__device__ __forceinline__ float bf2f(unsigned short h) {
    return __uint_as_float(((unsigned)h) << 16);
}
// scale a packed bf16 pair by dv (unpack-mul-repack)
__device__ __forceinline__ unsigned scale2(unsigned u, float dv) {
    float lo = __uint_as_float(u << 16) * dv;
    float hi = __uint_as_float(u & 0xFFFF0000u) * dv;
    return (((unsigned)f2bf(hi)) << 16) | (unsigned)f2bf(lo);
}

// ---------------- W transpose+convert: Wt[l][c*64+k] = bf16(W_l[k][c]) ----------------
__global__ __launch_bounds__(256) void k_prep(const float* __restrict__ W1, const float* __restrict__ W2,
                                              const float* __restrict__ W3, unsigned short* __restrict__ Wt) {
    const float* W = (blockIdx.x == 0) ? W1 : (blockIdx.x == 1) ? W2 : W3;
    unsigned short* o = Wt + blockIdx.x * 4096;
    int t = threadIdx.x;
    #pragma unroll
    for (int i = 0; i < 16; i++) {
        int e = i * 256 + t;                       // c = e>>6, k = e&63
        o[e] = f2bf(W[(e & 63) * 64 + (e >> 6)]);
    }
}

// ---------------- front kernel: scatter | zero(E1) | gemm1 (MFMA) ----------------
// payload: src(17b) | dstLow(8b)<<17
__global__ __launch_bounds__(256) void k_front(const int* __restrict__ src, const int* __restrict__ dst,
                                               int* __restrict__ bcur, int* __restrict__ binned,
                                               const float* __restrict__ x, const unsigned short* __restrict__ Wt1,
                                               unsigned short* __restrict__ P, float* __restrict__ zbase) {
    int bid = blockIdx.x;
    int t   = threadIdx.x;
    if (bid < NCHUNK) {
        // ---- scatter (bucket multisplit) ----
        __shared__ int stg[CHUNK];
        __shared__ unsigned short bkt[CHUNK];
        __shared__ int h[512], cur[512], off[512];
        __shared__ int ps[256];
        h[t] = 0; h[t + 256] = 0;
        __syncthreads();
        int base4 = bid * (CHUNK / 4);
        // phase 1: histogram (dst read #1)
        #pragma unroll
        for (int i = 0; i < CHUNK / 1024; i++) {
            int e4 = base4 + i * 256 + t;
            if (e4 < N_EDGES / 4) {
                int4 d = ((const int4*)dst)[e4];
                atomicAdd(&h[d.x >> 8], 1);
                atomicAdd(&h[d.y >> 8], 1);
                atomicAdd(&h[d.z >> 8], 1);
                atomicAdd(&h[d.w >> 8], 1);
            }
        }
        __syncthreads();
        // phase 2: pair-scan over 512 slots + global reservation; off = gbase - lbase
        int a0 = h[2 * t], a1 = h[2 * t + 1];
        ps[t] = a0 + a1;
        __syncthreads();
        for (int o = 1; o < 256; o <<= 1) {
            int v = (t >= o) ? ps[t - o] : 0;
            __syncthreads();
            if (t >= o) ps[t] += v;
            __syncthreads();
        }
        int pex = ps[t] - (a0 + a1);               // exclusive over pairs
        int e0 = pex, e1 = pex + a0;
        cur[2 * t] = e0; cur[2 * t + 1] = e1;
        if (2 * t < SB && a0 > 0)
            off[2 * t] = (2 * t) * CAP + atomicAdd(&bcur[2 * t], a0) - e0;
        if (2 * t + 1 < SB && a1 > 0)
            off[2 * t + 1] = (2 * t + 1) * CAP + atomicAdd(&bcur[2 * t + 1], a1) - e1;
        __syncthreads();
        int total = ps[255];                        // edges in this chunk
        // phase 3: re-read dst (+src), stage payload + bucket id
        #pragma unroll
        for (int i = 0; i < CHUNK / 1024; i++) {
            int e4 = base4 + i * 256 + t;
            if (e4 < N_EDGES / 4) {
                int4 d  = ((const int4*)dst)[e4];   // L2-hot re-read
                int4 s4 = ((const int4*)src)[e4];
                int q;
                q = atomicAdd(&cur[d.x >> 8], 1); stg[q] = s4.x | ((d.x & 255) << 17); bkt[q] = (unsigned short)(d.x >> 8);
                q = atomicAdd(&cur[d.y >> 8], 1); stg[q] = s4.y | ((d.y & 255) << 17); bkt[q] = (unsigned short)(d.y >> 8);
                q = atomicAdd(&cur[d.z >> 8], 1); stg[q] = s4.z | ((d.z & 255) << 17); bkt[q] = (unsigned short)(d.z >> 8);
                q = atomicAdd(&cur[d.w >> 8], 1); stg[q] = s4.w | ((d.w & 255) << 17); bkt[q] = (unsigned short)(d.w >> 8);
            }
        }
        __syncthreads();
        // phase 4: flat flush — coalesced LDS read, run-coalesced global write
        for (int i = t; i < total; i += 256) {
            int b = bkt[i];
            binned[off[b] + i] = stg[i];
        }
    } else if (bid < NCHUNK + NZB) {
        // ---- zero E1 ----
        float4 z = make_float4(0.f, 0.f, 0.f, 0.f);
        float4* zp = (float4*)zbase;
        int zb = bid - NCHUNK;
        for (long i = (long)zb * 256 + t; i < (long)ZLEN4_F; i += (long)NZB * 256)
            zp[i] = z;
    } else {
        // ---- gemm1 (MFMA): P = bf16(x @ W1), unscaled (k_bcsr scales by dinv later) ----
        __shared__ unsigned short xin_s[128 * LW];
        __shared__ unsigned short wt_s[64 * LW];
        int nb = (bid - NCHUNK - NZB) * 128;
        #pragma unroll
        for (int i = 0; i < 16; i++) {             // stage Wt1 -> LDS
            int e = i * 256 + t;
            wt_s[(e >> 6) * LW + (e & 63)] = Wt1[e];
        }
        #pragma unroll
        for (int i = 0; i < 8; i++) {              // stage x rows (bf16) -> LDS
            int f = i * 256 + t;
            int row = f >> 4, q = f & 15;
            int gR = nb + row;
            unsigned u0 = 0, u1 = 0;
            if (gR < N_NODES) {
                float4 xv = ((const float4*)x)[(size_t)gR * 16 + q];
                u0 = ((unsigned)f2bf(xv.y) << 16) | f2bf(xv.x);
                u1 = ((unsigned)f2bf(xv.w) << 16) | f2bf(xv.z);
            }
            *(uint2*)&xin_s[row * LW + q * 4] = make_uint2(u0, u1);
        }
        __syncthreads();
        int lane = t & 63, w = t >> 6;
        int l15 = lane & 15, l4 = lane >> 4;
        B128 bfr[4][2];
        #pragma unroll
        for (int nt = 0; nt < 4; nt++)
            #pragma unroll
            for (int ks = 0; ks < 2; ks++)
                bfr[nt][ks].u = *(const uint4*)&wt_s[(nt * 16 + l15) * LW + ks * 32 + l4 * 8];
        f32x4 acc[2][4] = {};
        #pragma unroll
        for (int m = 0; m < 2; m++) {
            int rb = w * 32 + m * 16;
            B128 a0, a1;
            a0.u = *(const uint4*)&xin_s[(rb + l15) * LW +  0 + l4 * 8];
            a1.u = *(const uint4*)&xin_s[(rb + l15) * LW + 32 + l4 * 8];
            #pragma unroll
            for (int nt = 0; nt < 4; nt++) {
                acc[m][nt] = __builtin_amdgcn_mfma_f32_16x16x32_bf16(a0.b, bfr[nt][0].b, acc[m][nt], 0, 0, 0);
                acc[m][nt] = __builtin_amdgcn_mfma_f32_16x16x32_bf16(a1.b, bfr[nt][1].b, acc[m][nt], 0, 0, 0);
            }
        }
        #pragma unroll
        for (int m = 0; m < 2; m++) {
            int Rbase = nb + w * 32 + m * 16;
            #pragma unroll
            for (int nt = 0; nt < 4; nt++)
                #pragma unroll
                for (int r = 0; r < 4; r++) {
                    int row = Rbase + l4 * 4 + r;   // C layout: col=lane&15, row=(lane>>4)*4+reg [m89]
                    if (row < N_NODES)
                        P[(size_t)row * 64 + nt * 16 + l15] = f2bf(acc[m][nt][r]);
                }
        }
    }
}

// ---------------- per-bucket: degrees -> dinv/dinv2 + LDS-staged csr + P pre-scale ----------------
// (proven r10 form: 1024 thr, binned staged once in LDS, csr built in LDS then flushed coalesced)
__global__ __launch_bounds__(1024) void k_bcsr(const int* __restrict__ binned, const int* __restrict__ bcur,
                                               float* __restrict__ dinv, float* __restrict__ dinv2,
                                               int* __restrict__ csr, unsigned short* __restrict__ P) {
    __shared__ int bin_s[CAP];
    __shared__ int cs_s[CAP];
    __shared__ int h[NPB];
    __shared__ int ts[NPB];
    __shared__ float sdv[NPB];
    int t = threadIdx.x;
    int b = blockIdx.x;
    int nb0  = b << 8;
    int ebeg = b * CAP;
    int ecnt = bcur[b]; if (ecnt > CAP) ecnt = CAP;
    if (t < NPB) h[t] = 0;
    __syncthreads();
    for (int i = t; i < ecnt; i += 1024) {
        int p = binned[ebeg + i];
        bin_s[i] = p;
        atomicAdd(&h[p >> 17], 1);
    }
    __syncthreads();
    int c = 0;
    if (t < NPB) { c = h[t]; ts[t] = c; }
    __syncthreads();
    for (int o = 1; o < NPB; o <<= 1) {
        int v = (t >= o && t < NPB) ? ts[t - o] : 0;
        __syncthreads();
        if (t >= o && t < NPB) ts[t] += v;
        __syncthreads();
    }
    if (t < NPB) {
        int n = nb0 + t;
        float dval = 0.f;
        if (n < N_NODES) {
            float inv = 1.0f / (float)(c + 1);     // +1 self loop
            dinv2[n] = inv;
            dval     = sqrtf(inv);
            dinv[n]  = dval;
        }
        sdv[t] = dval;
        h[t] = ts[t] - c;                          // local write cursor (0-based in bucket)
    }
    __syncthreads();
    for (int i = t; i < ecnt; i += 1024) {
        int p = bin_s[i];
        int q = atomicAdd(&h[p >> 17], 1);
        cs_s[q] = p;                               // keep src | dstLow<<17
    }
    __syncthreads();
    for (int i = t; i < ecnt; i += 1024)
        csr[ebeg + i] = cs_s[i];
    // ---- scale this bucket's P rows by dinv (8 uint4 = 64 bf16 per row) ----
    for (int i = t; i < NPB * 8; i += 1024) {
        int row = i >> 3;
        int nn  = nb0 + row;
        if (nn >= N_NODES) break;                  // row monotone in i per thread
        float dv = sdv[row];
        uint4* pp = (uint4*)P + (size_t)nn * 8 + (i & 7);
        uint4 v = *pp;
        v.x = scale2(v.x, dv); v.y = scale2(v.y, dv);
        v.z = scale2(v.z, dv); v.w = scale2(v.w, dv);
        *pp = v;
    }
}

// ---------------- GEMM layers 2/3 (MFMA; proven r11 form) ----------------
template<bool POOLI>
__global__ __launch_bounds__(256) void k_gemm(const float* __restrict__ E,
                                              unsigned short* P,            // aliased in/out (row-private)
                                              const unsigned short* __restrict__ Wt,
                                              const float* __restrict__ bprev,
                                              const float* __restrict__ bcurr,
                                              const float* __restrict__ dinv,
                                              const float* __restrict__ dinv2,
                                              const int* __restrict__ batch,
                                              float* __restrict__ pool) {
    __shared__ unsigned short xin_s[128 * LW];
    __shared__ unsigned short wt_s[64 * LW];
    int t  = threadIdx.x;
    int nb = blockIdx.x * 128;
    #pragma unroll
    for (int i = 0; i < 16; i++) {                 // stage Wt -> LDS
        int e = i * 256 + t;
        wt_s[(e >> 6) * LW + (e & 63)] = Wt[e];
    }
    #pragma unroll
    for (int i = 0; i < 8; i++) {                  // stage xin rows (bf16) -> LDS
        int f = i * 256 + t;
        int row = f >> 4, q = f & 15;
        int gR = nb + row;
        unsigned u0 = 0, u1 = 0;
        if (gR < N_NODES) {
            float4  ev = ((const float4*)E)[(size_t)gR * 16 + q];
            ushort4 pv = ((const ushort4*)P)[(size_t)gR * 16 + q];
            float dn = dinv[gR];
            float4 bp = ((const float4*)bprev)[q];
            float x0 = fmaxf(ev.x + fmaf(bf2f(pv.x), dn, bp.x), 0.f);
            float x1 = fmaxf(ev.y + fmaf(bf2f(pv.y), dn, bp.y), 0.f);
            float x2 = fmaxf(ev.z + fmaf(bf2f(pv.z), dn, bp.z), 0.f);
            float x3 = fmaxf(ev.w + fmaf(bf2f(pv.w), dn, bp.w), 0.f);
            u0 = ((unsigned)f2bf(x1) << 16) | f2bf(x0);
            u1 = ((unsigned)f2bf(x3) << 16) | f2bf(x2);
        }
        *(uint2*)&xin_s[row * LW + q * 4] = make_uint2(u0, u1);
    }
    __syncthreads();
    int lane = t & 63, w = t >> 6;
    int l15 = lane & 15, l4 = lane >> 4;
    B128 bfr[4][2];
    #pragma unroll
    for (int nt = 0; nt < 4; nt++)
        #pragma unroll
        for (int ks = 0; ks < 2; ks++)
            bfr[nt][ks].u = *(const uint4*)&wt_s[(nt * 16 + l15) * LW + ks * 32 + l4 * 8];
    f32x4 acc[2][4] = {};
    #pragma unroll
    for (int m = 0; m < 2; m++) {
        int rb = w * 32 + m * 16;
        B128 a0, a1;
        a0.u = *(const uint4*)&xin_s[(rb + l15) * LW +  0 + l4 * 8];
        a1.u = *(const uint4*)&xin_s[(rb + l15) * LW + 32 + l4 * 8];
        #pragma unroll
        for (int nt = 0; nt < 4; nt++) {
            acc[m][nt] = __builtin_amdgcn_mfma_f32_16x16x32_bf16(a0.b, bfr[nt][0].b, acc[m][nt], 0, 0, 0);
            acc[m][nt] = __builtin_amdgcn_mfma_f32_16x16x32_bf16(a1.b, bfr[nt][1].b, acc[m][nt], 0, 0, 0);
        }
    }
    #pragma unroll
    for (int m = 0; m < 2; m++) {
        int Rbase = nb + w * 32 + m * 16;
        float dnr[4], d2r[4];
        #pragma unroll
        for (int r = 0; r < 4; r++) {
            int row = Rbase + l4 * 4 + r;
            bool v = row < N_NODES;
            dnr[r] = v ? dinv[row] : 0.f;
            d2r[r] = (POOLI && v) ? dinv2[row] : 0.f;
        }
        #pragma unroll
        for (int nt = 0; nt < 4; nt++)
            #pragma unroll
            for (int r = 0; r < 4; r++) {
                int row = Rbase + l4 * 4 + r;       // C layout: col=lane&15, row=(lane>>4)*4+reg [m89]
                if (row < N_NODES)
                    P[(size_t)row * 64 + nt * 16 + l15] = f2bf(acc[m][nt][r] * dnr[r]);
            }
        if (POOLI) {
            bool full = (Rbase + 15) < N_NODES;
            int g0 = -1, g15 = -2;
            if (full) { g0 = batch[Rbase]; g15 = batch[Rbase + 15]; }
            if (full && g0 == g15) {
                #pragma unroll
                for (int nt = 0; nt < 4; nt++) {
                    float v = 0.f;
                    #pragma unroll
                    for (int r = 0; r < 4; r++) v = fmaf(acc[m][nt][r], d2r[r], v);
                    v += __shfl_xor(v, 16);
                    v += __shfl_xor(v, 32);
                    if (lane < 16)
                        atomicAdd(&pool[g0 * 64 + nt * 16 + lane], fmaf(16.f, bcurr[nt * 16 + lane], v));
                }
            } else if (Rbase < N_NODES) {
                #pragma unroll
                for (int nt = 0; nt < 4; nt++) {
                    float bc = bcurr[nt * 16 + l15];
                    #pragma unroll
                    for (int r = 0; r < 4; r++) {
                        int row = Rbase + l4 * 4 + r;
                        if (row < N_NODES)
                            atomicAdd(&pool[batch[row] * 64 + nt * 16 + l15], fmaf(acc[m][nt][r], d2r[r], bc));
                    }
                }
            }
        }
    }
}

// ---------------- Edge-parallel aggregation (bf16 gather; interior-run plain stores) ----------------
// Wave owns 64 csr slots (node-sorted runs within one bucket).
// Out[dst] += dinv[dst] * sum(Pscaled[src])
// r12: runs NOT touching a window boundary are wave-EXCLUSIVE (node's edges entirely in
// this window, since csr is node-sorted and windows are contiguous) -> flush with a plain
// coalesced 256B store (no read-for-RMW fetch of the E line). Only the first run (if a
// left-neighbor window exists) and the last run (if a right-neighbor exists) keep the
// atomic. Decision flags are wave-uniform SGPRs -> zero per-edge cost. Pre-zeroed E still
// covers boundary + deg-0 nodes. POOLEP (layer 3): always atomic (pool is shared).
// ZROLE: trailing NZB2 blocks zero the pool|E2 span (rides agge1's latency shadow).
template<bool POOLEP, bool ZROLE>
__global__ __launch_bounds__(256, 8) void k_agge(const unsigned short* __restrict__ Hbuf,
                                                 const int* __restrict__ csr,
                                                 const int* __restrict__ bcur,
                                                 const float* __restrict__ dinv,
                                                 const int* __restrict__ batch,
                                                 float* __restrict__ Out,
                                                 float* __restrict__ zbase) {
    int t = threadIdx.x;
    if (ZROLE && blockIdx.x >= AGGE_GRID) {
        float4 z = make_float4(0.f, 0.f, 0.f, 0.f);
        float4* zp = (float4*)zbase;
        int zb = blockIdx.x - AGGE_GRID;
        for (long i = (long)zb * 256 + t; i < (long)ZLEN4_A; i += (long)NZB2 * 256)
            zp[i] = z;
        return;
    }
    int wv   = t >> 6;
    int lane = t & 63;
    int wid  = blockIdx.x * 4 + wv;                // 0 .. SB*WPB-1
    int b    = wid / WPB;
    int lw   = wid - b * WPB;
    int used = bcur[b]; if (used > CAP) used = CAP;
    int e0   = lw * 64;
    int rem  = used - e0;
    if (rem <= 0) return;
    if (rem > 64) rem = 64;
    int base = b * CAP + e0;

    int p = 0;
    if (lane < rem) p = csr[base + lane];          // coalesced 256B (only load in init)
    int sv = p & 0x1FFFF;
    int dv = p >> 17;                              // dstLow (8b)

    // wave-uniform run-start mask (bit i: slot i starts a new dst run); bit 0 cleared
    int dvp = __shfl_up(dv, 1);
    unsigned long long m0 = __ballot(dv != dvp);
    unsigned mlo = __builtin_amdgcn_readfirstlane((unsigned)m0);
    unsigned mhi = __builtin_amdgcn_readfirstlane((unsigned)(m0 >> 32));
    unsigned long long mask = ((((unsigned long long)mhi) << 32) | mlo) & ~1ull;

    bool contL = (lw > 0);                         // run at slot 0 may continue left
    bool contR = (e0 + rem < used);                // run at slot rem-1 may continue right

    auto flush1 = [&](int dl, float a, bool atom) {
        int dst = (b << 8) + dl;
        if (dst < N_NODES) {
            float val = dinv[dst] * a;             // uniform load
            if (POOLEP) {
                int g = batch[dst];                // uniform load
                atomicAdd(&Out[g * 64 + lane], val);
            } else if (atom) {
                atomicAdd(&Out[(size_t)dst * 64 + lane], val);
            } else {
                Out[(size_t)dst * 64 + lane] = val; // exclusive run: plain store
            }
        }
    };

    int cur = rl_i(dv, 0);
    float acc = 0.f;
    bool first = true;                             // wave-uniform
    int j = 0;
    for (; j + 16 <= rem; j += 16) {
        unsigned short u[16];
        #pragma unroll
        for (int i = 0; i < 16; i++) {             // 16 gathers issued up front (r0 form)
            int s = rl_i(sv, j + i);
            u[i] = Hbuf[(size_t)s * 64 + lane];
        }
        #pragma unroll
        for (int i = 0; i < 16; i++) {
            if ((mask >> (j + i)) & 1) {           // scalar bit-test + scalar branch
                flush1(cur, acc, first && contL); first = false;
                acc = 0.f; cur = rl_i(dv, j + i);
            }
            acc += bf2f(u[i]);                     // 2 VALU/edge
        }
    }
    for (; j < rem; j++) {
        int s0 = rl_i(sv, j);
        unsigned short u0 = Hbuf[(size_t)s0 * 64 + lane];
        if ((mask >> j) & 1) {
            flush1(cur, acc, first && contL); first = false;
            acc = 0.f; cur = rl_i(dv, j);
        }
        acc += bf2f(u0);
    }
    flush1(cur, acc, (first && contL) || contR);
}

// ---------------- mean + classifier ----------------
__device__ __forceinline__ int lbound(const int* __restrict__ a, int n, int v) {
    int lo = 0, hi = n;
    while (lo < hi) { int m = (lo + hi) >> 1; if (a[m] < v) lo = m + 1; else hi = m; }
    return lo;
}

__global__ __launch_bounds__(64) void k_cls(const float* __restrict__ pool, const int* __restrict__ batch,
                                            const float* __restrict__ Wl, const float* __restrict__ bl,
                                            float* __restrict__ out) {
    __shared__ float pm[64];
    __shared__ int bounds[2];
    int g = blockIdx.x;
    int t = threadIdx.x;
    if (t < 2) bounds[t] = lbound(batch, N_NODES, g + t);
    __syncthreads();
    float cnt = (float)(bounds[1] - bounds[0]);
    pm[t] = pool[g * 64 + t] / fmaxf(cnt, 1.0f);
    __syncthreads();
    if (t < N_CLASSES) {
        float o = bl[t];
        #pragma unroll
        for (int k = 0; k < HID; k++) o = fmaf(pm[k], Wl[k * N_CLASSES + t], o);
        out[g * N_CLASSES + t] = o;
    }
}

// ---------------- launch ----------------

extern "C" void kernel_launch(void* const* d_in, const int* in_sizes, int n_in,
                              void* d_out, int out_size, void* d_ws, size_t ws_size,
                              hipStream_t stream) {
    const float* x     = (const float*)d_in[0];
    const int*   eidx  = (const int*)  d_in[1];
    const int*   batch = (const int*)  d_in[2];
    const float* W1 = (const float*)d_in[3];
    const float* b1 = (const float*)d_in[4];
    const float* W2 = (const float*)d_in[5];
    const float* b2 = (const float*)d_in[6];
    const float* W3 = (const float*)d_in[7];
    const float* b3 = (const float*)d_in[8];
    const float* Wl = (const float*)d_in[9];
    const float* bl = (const float*)d_in[10];
    const int* src = eidx;
    const int* dst = eidx + N_EDGES;

    char* p = (char*)d_ws;
    auto alloc = [&](size_t bytes) -> void* {
        void* r = (void*)p;
        p += (bytes + 255) & ~(size_t)255;
        return r;
    };
    float* dinv  = (float*)alloc((size_t)N_NODES * 4);
    float* dinv2 = (float*)alloc((size_t)N_NODES * 4);
    int*   csr   = (int*)  alloc((size_t)SB * CAP * 4);
    unsigned short* P = (unsigned short*)alloc((size_t)N_NODES * 64 * 2);  // bf16 H (scaled)
    float* E1    = (float*)alloc((size_t)N_NODES * 64 * 4);   // edge sums L1
    float* pool  = (float*)alloc((size_t)N_GRAPHS * 64 * 4);  // contiguous after E1
    float* E2    = (float*)alloc((size_t)N_NODES * 64 * 4);   // contiguous after pool
    int*   bcur  = (int*)  alloc((size_t)SB * 4);
    int*   binned = (int*) alloc((size_t)SB * CAP * 4);
    unsigned short* Wt = (unsigned short*)alloc((size_t)3 * 4096 * 2);  // bf16 W^T x3

    const int front_grid = NCHUNK + NZB + GEMM_GRID;

    // ---- prep: W -> bf16 transposed ----
    hipMemsetAsync(bcur, 0, (size_t)SB * 4, stream);
    k_prep<<<3, 256, 0, stream>>>(W1, W2, W3, Wt);
    // ---- front: scatter | zero(E1) | gemm1-MFMA (all independent) ----
    k_front<<<front_grid, 256, 0, stream>>>(src, dst, bcur, binned, x, Wt, P, E1);
    // bcsr: degrees + LDS-staged csr fill + in-place scale P1 *= dinv (1024 thr)
    k_bcsr <<<SB, 1024, 0, stream>>>(binned, bcur, dinv, dinv2, csr, P);

    // layer 1 edges: scaled-H1 gathers -> E1 ; trailing blocks zero pool|E2
    k_agge<false, true ><<<AGGE_GRID + NZB2, 256, 0, stream>>>(P, csr, bcur, dinv, batch, E1, pool);
    // layer 2: relu(E1 + b1 + Ps*dinv) @ W2 -> H2 (scaled, in-place in P); edges -> E2
    k_gemm<false><<<GEMM_GRID, 256, 0, stream>>>(E1, P, Wt + 4096, b1, nullptr, dinv, dinv2, batch, nullptr);
    k_agge<false, false><<<AGGE_GRID, 256, 0, stream>>>(P, csr, bcur, dinv, batch, E2, nullptr);
    // layer 3: relu(E2 + b2 + Ps*dinv) @ W3 -> H3; self terms -> pool; edges -> pool
    k_gemm<true ><<<GEMM_GRID, 256, 0, stream>>>(E2, P, Wt + 8192, b2, b3, dinv, dinv2, batch, pool);
    k_agge<true , false><<<AGGE_GRID, 256, 0, stream>>>(P, csr, bcur, dinv, batch, pool, nullptr);

    // mean + classifier
    k_cls<<<N_GRAPHS, 64, 0, stream>>>(pool, batch, Wl, bl, (float*)d_out);
}

// Round 13
// 308.873 us; speedup vs baseline: 1.7868x; 1.0011x over previous
//
#include <hip/hip_runtime.h>
#include <hip/hip_bf16.h>

#define N_NODES   100000
#define N_EDGES   1600000
#define F_IN      64
#define HID       64
#define N_CLASSES 45
#define N_GRAPHS  256
#define SB        392         // super-buckets: bucket = dst >> 8 (0..390)
#define NPB       256         // nodes per bucket
#define CAP       4608        // fixed bucket capacity; 4608 = 72*64 (mean 4082, sigma 64 -> +8s)
#define WPB       72          // waves per bucket in k_agge (CAP/64)
#define CHUNK     4096        // edges per scatter workgroup
#define NCHUNK    391         // ceil(N_EDGES / CHUNK)
#define GEMM_GRID 782         // ceil(N_NODES / 128) MFMA gemm blocks
#define AGGE_GRID 7056        // SB*WPB/4
#define LW        72          // LDS row stride in bf16 elems (64+8 -> 144B, 2-way-conflict free)

typedef __attribute__((ext_vector_type(8))) short bf16x8;
typedef __attribute__((ext_vector_type(4))) float f32x4;
union B128 { uint4 u; bf16x8 b; };

__device__ __forceinline__ float rl_f(float v, int k) {
    return __uint_as_float(__builtin_amdgcn_readlane(__float_as_uint(v), k));
}
__device__ __forceinline__ int rl_i(int v, int k) {
    return __builtin_amdgcn_readlane(v, k);
}
// fp32 <-> bf16 (RNE)
__device__ __forceinline__ unsigned short f2bf(float x) {
    unsigned u = __float_as_uint(x);
    unsigned r = u + 0x7FFFu + ((u >> 16) & 1u);
    return (unsigned short)(r >> 16);
}
__device__ __forceinline__ float bf2f(unsigned short h) {
    return __uint_as_float(((unsigned)h) << 16);
}
// scale a packed bf16 pair by dv (unpack-mul-repack)
__device__ __forceinline__ unsigned scale2(unsigned u, float dv) {
    float lo = __uint_as_float(u << 16) * dv;
    float hi = __uint_as_float(u & 0xFFFF0000u) * dv;
    return (((unsigned)f2bf(hi)) << 16) | (unsigned)f2bf(lo);
}

// ---------------- front kernel: scatter | gemm1 (MFMA, inline W1 convert) ----------------
// payload: src(17b) | dstLow(8b)<<17
__global__ __launch_bounds__(256) void k_front(const int* __restrict__ src, const int* __restrict__ dst,
                                               int* __restrict__ bcur, int* __restrict__ binned,
                                               const float* __restrict__ x, const float* __restrict__ W1,
                                               unsigned short* __restrict__ P) {
    int bid = blockIdx.x;
    int t   = threadIdx.x;
    if (bid < NCHUNK) {
        // ---- scatter (bucket multisplit) ----
        __shared__ int stg[CHUNK];
        __shared__ unsigned short bkt[CHUNK];
        __shared__ int h[512], cur[512], off[512];
        __shared__ int ps[256];
        h[t] = 0; h[t + 256] = 0;
        __syncthreads();
        int base4 = bid * (CHUNK / 4);
        // phase 1: histogram (dst read #1)
        #pragma unroll
        for (int i = 0; i < CHUNK / 1024; i++) {
            int e4 = base4 + i * 256 + t;
            if (e4 < N_EDGES / 4) {
                int4 d = ((const int4*)dst)[e4];
                atomicAdd(&h[d.x >> 8], 1);
                atomicAdd(&h[d.y >> 8], 1);
                atomicAdd(&h[d.z >> 8], 1);
                atomicAdd(&h[d.w >> 8], 1);
            }
        }
        __syncthreads();
        // phase 2: pair-scan over 512 slots + global reservation; off = gbase - lbase
        int a0 = h[2 * t], a1 = h[2 * t + 1];
        ps[t] = a0 + a1;
        __syncthreads();
        for (int o = 1; o < 256; o <<= 1) {
            int v = (t >= o) ? ps[t - o] : 0;
            __syncthreads();
            if (t >= o) ps[t] += v;
            __syncthreads();
        }
        int pex = ps[t] - (a0 + a1);               // exclusive over pairs
        int e0 = pex, e1 = pex + a0;
        cur[2 * t] = e0; cur[2 * t + 1] = e1;
        if (2 * t < SB && a0 > 0)
            off[2 * t] = (2 * t) * CAP + atomicAdd(&bcur[2 * t], a0) - e0;
        if (2 * t + 1 < SB && a1 > 0)
            off[2 * t + 1] = (2 * t + 1) * CAP + atomicAdd(&bcur[2 * t + 1], a1) - e1;
        __syncthreads();
        int total = ps[255];                        // edges in this chunk
        // phase 3: re-read dst (+src), stage payload + bucket id
        #pragma unroll
        for (int i = 0; i < CHUNK / 1024; i++) {
            int e4 = base4 + i * 256 + t;
            if (e4 < N_EDGES / 4) {
                int4 d  = ((const int4*)dst)[e4];   // L2-hot re-read
                int4 s4 = ((const int4*)src)[e4];
                int q;
                q = atomicAdd(&cur[d.x >> 8], 1); stg[q] = s4.x | ((d.x & 255) << 17); bkt[q] = (unsigned short)(d.x >> 8);
                q = atomicAdd(&cur[d.y >> 8], 1); stg[q] = s4.y | ((d.y & 255) << 17); bkt[q] = (unsigned short)(d.y >> 8);
                q = atomicAdd(&cur[d.z >> 8], 1); stg[q] = s4.z | ((d.z & 255) << 17); bkt[q] = (unsigned short)(d.z >> 8);
                q = atomicAdd(&cur[d.w >> 8], 1); stg[q] = s4.w | ((d.w & 255) << 17); bkt[q] = (unsigned short)(d.w >> 8);
            }
        }
        __syncthreads();
        // phase 4: flat flush — coalesced LDS read, run-coalesced global write
        for (int i = t; i < total; i += 256) {
            int b = bkt[i];
            binned[off[b] + i] = stg[i];
        }
    } else {
        // ---- gemm1 (MFMA): P = bf16(x @ W1), unscaled (k_bcsr scales by dinv later) ----
        __shared__ unsigned short xin_s[128 * LW];
        __shared__ unsigned short wt_s[64 * LW];
        int nb = (bid - NCHUNK) * 128;
        #pragma unroll
        for (int i = 0; i < 16; i++) {             // stage W1^T (f32->bf16 inline, L2-hot)
            int e = i * 256 + t;                   // c = e>>6, k = e&63
            wt_s[(e >> 6) * LW + (e & 63)] = f2bf(W1[(e & 63) * 64 + (e >> 6)]);
        }
        #pragma unroll
        for (int i = 0; i < 8; i++) {              // stage x rows (bf16) -> LDS
            int f = i * 256 + t;
            int row = f >> 4, q = f & 15;
            int gR = nb + row;
            unsigned u0 = 0, u1 = 0;
            if (gR < N_NODES) {
                float4 xv = ((const float4*)x)[(size_t)gR * 16 + q];
                u0 = ((unsigned)f2bf(xv.y) << 16) | f2bf(xv.x);
                u1 = ((unsigned)f2bf(xv.w) << 16) | f2bf(xv.z);
            }
            *(uint2*)&xin_s[row * LW + q * 4] = make_uint2(u0, u1);
        }
        __syncthreads();
        int lane = t & 63, w = t >> 6;
        int l15 = lane & 15, l4 = lane >> 4;
        B128 bfr[4][2];
        #pragma unroll
        for (int nt = 0; nt < 4; nt++)
            #pragma unroll
            for (int ks = 0; ks < 2; ks++)
                bfr[nt][ks].u = *(const uint4*)&wt_s[(nt * 16 + l15) * LW + ks * 32 + l4 * 8];
        f32x4 acc[2][4] = {};
        #pragma unroll
        for (int m = 0; m < 2; m++) {
            int rb = w * 32 + m * 16;
            B128 a0, a1;
            a0.u = *(const uint4*)&xin_s[(rb + l15) * LW +  0 + l4 * 8];
            a1.u = *(const uint4*)&xin_s[(rb + l15) * LW + 32 + l4 * 8];
            #pragma unroll
            for (int nt = 0; nt < 4; nt++) {
                acc[m][nt] = __builtin_amdgcn_mfma_f32_16x16x32_bf16(a0.b, bfr[nt][0].b, acc[m][nt], 0, 0, 0);
                acc[m][nt] = __builtin_amdgcn_mfma_f32_16x16x32_bf16(a1.b, bfr[nt][1].b, acc[m][nt], 0, 0, 0);
            }
        }
        #pragma unroll
        for (int m = 0; m < 2; m++) {
            int Rbase = nb + w * 32 + m * 16;
            #pragma unroll
            for (int nt = 0; nt < 4; nt++)
                #pragma unroll
                for (int r = 0; r < 4; r++) {
                    int row = Rbase + l4 * 4 + r;   // C layout: col=lane&15, row=(lane>>4)*4+reg [m89]
                    if (row < N_NODES)
                        P[(size_t)row * 64 + nt * 16 + l15] = f2bf(acc[m][nt][r]);
                }
        }
    }
}

// ---------------- per-bucket: degrees -> dinv/dinv2 + LDS-staged csr + P pre-scale ----------------
// + r13: selective E zeroing — only nodes whose run crosses a 64-slot window boundary
//   (flushed by atomic in k_agge) or deg-0 nodes need zeroed E rows; interior nodes are
//   fully written by plain stores. Replaces the 51MB full E1/E2 pre-zero roles.
// + r13: blocks SB..SB+1 transpose W2/W3 -> bf16 Wt (replaces k_prep launch).
__global__ __launch_bounds__(1024) void k_bcsr(const int* __restrict__ binned, const int* __restrict__ bcur,
                                               float* __restrict__ dinv, float* __restrict__ dinv2,
                                               int* __restrict__ csr, unsigned short* __restrict__ P,
                                               const float* __restrict__ W2, const float* __restrict__ W3,
                                               unsigned short* __restrict__ Wt,
                                               float* __restrict__ E1, float* __restrict__ E2) {
    int t = threadIdx.x;
    int b = blockIdx.x;
    if (b >= SB) {                                 // ---- W2/W3 transpose role ----
        const float* W = (b == SB) ? W2 : W3;
        unsigned short* o = Wt + (b - SB) * 4096;
        for (int i = t; i < 4096; i += 1024)
            o[i] = f2bf(W[(i & 63) * 64 + (i >> 6)]);
        return;
    }
    __shared__ int bin_s[CAP];
    __shared__ int cs_s[CAP];
    __shared__ int h[NPB];
    __shared__ int ts[NPB];
    __shared__ float sdv[NPB];
    __shared__ unsigned short zlist[NPB];
    __shared__ int zcnt;
    int nb0  = b << 8;
    int ebeg = b * CAP;
    int ecnt = bcur[b]; if (ecnt > CAP) ecnt = CAP;
    if (t < NPB) h[t] = 0;
    if (t == 0) zcnt = 0;
    __syncthreads();
    for (int i = t; i < ecnt; i += 1024) {
        int p = binned[ebeg + i];
        bin_s[i] = p;
        atomicAdd(&h[p >> 17], 1);
    }
    __syncthreads();
    int c = 0;
    if (t < NPB) { c = h[t]; ts[t] = c; }
    __syncthreads();
    for (int o = 1; o < NPB; o <<= 1) {
        int v = (t >= o && t < NPB) ? ts[t - o] : 0;
        __syncthreads();
        if (t >= o && t < NPB) ts[t] += v;
        __syncthreads();
    }
    if (t < NPB) {
        int n  = nb0 + t;
        int el = ts[t] - c;                        // local (0-based) csr start
        float dval = 0.f;
        if (n < N_NODES) {
            float inv = 1.0f / (float)(c + 1);     // +1 self loop
            dinv2[n] = inv;
            dval     = sqrtf(inv);
            dinv[n]  = dval;
            // boundary-crossing or deg-0 -> E row written by atomics (or not at all)
            if (c == 0 || (el >> 6) != ((el + c - 1) >> 6)) {
                int q = atomicAdd(&zcnt, 1);
                zlist[q] = (unsigned short)t;
            }
        }
        sdv[t] = dval;
        h[t] = el;                                 // local write cursor
    }
    __syncthreads();
    for (int i = t; i < ecnt; i += 1024) {
        int p = bin_s[i];
        int q = atomicAdd(&h[p >> 17], 1);
        cs_s[q] = p;                               // keep src | dstLow<<17
    }
    int nz = zcnt;
    __syncthreads();
    for (int i = t; i < ecnt; i += 1024)
        csr[ebeg + i] = cs_s[i];
    // ---- selective zero of boundary/deg-0 E rows (16 float4 per row, both layers) ----
    float4 z4 = make_float4(0.f, 0.f, 0.f, 0.f);
    for (int i = t; i < nz * 16; i += 1024) {
        size_t row = (size_t)(nb0 + zlist[i >> 4]);
        ((float4*)E1)[row * 16 + (i & 15)] = z4;
        ((float4*)E2)[row * 16 + (i & 15)] = z4;
    }
    // ---- scale this bucket's P rows by dinv (8 uint4 = 64 bf16 per row) ----
    for (int i = t; i < NPB * 8; i += 1024) {
        int row = i >> 3;
        int nn  = nb0 + row;
        if (nn >= N_NODES) break;                  // row monotone in i per thread
        float dv = sdv[row];
        uint4* pp = (uint4*)P + (size_t)nn * 8 + (i & 7);
        uint4 v = *pp;
        v.x = scale2(v.x, dv); v.y = scale2(v.y, dv);
        v.z = scale2(v.z, dv); v.w = scale2(v.w, dv);
        *pp = v;
    }
}

// ---------------- GEMM layers 2/3 (MFMA; proven r11 form) ----------------
template<bool POOLI>
__global__ __launch_bounds__(256) void k_gemm(const float* __restrict__ E,
                                              unsigned short* P,            // aliased in/out (row-private)
                                              const unsigned short* __restrict__ Wt,
                                              const float* __restrict__ bprev,
                                              const float* __restrict__ bcurr,
                                              const float* __restrict__ dinv,
                                              const float* __restrict__ dinv2,
                                              const int* __restrict__ batch,
                                              float* __restrict__ pool) {
    __shared__ unsigned short xin_s[128 * LW];
    __shared__ unsigned short wt_s[64 * LW];
    int t  = threadIdx.x;
    int nb = blockIdx.x * 128;
    #pragma unroll
    for (int i = 0; i < 16; i++) {                 // stage Wt -> LDS
        int e = i * 256 + t;
        wt_s[(e >> 6) * LW + (e & 63)] = Wt[e];
    }
    #pragma unroll
    for (int i = 0; i < 8; i++) {                  // stage xin rows (bf16) -> LDS
        int f = i * 256 + t;
        int row = f >> 4, q = f & 15;
        int gR = nb + row;
        unsigned u0 = 0, u1 = 0;
        if (gR < N_NODES) {
            float4  ev = ((const float4*)E)[(size_t)gR * 16 + q];
            ushort4 pv = ((const ushort4*)P)[(size_t)gR * 16 + q];
            float dn = dinv[gR];
            float4 bp = ((const float4*)bprev)[q];
            float x0 = fmaxf(ev.x + fmaf(bf2f(pv.x), dn, bp.x), 0.f);
            float x1 = fmaxf(ev.y + fmaf(bf2f(pv.y), dn, bp.y), 0.f);
            float x2 = fmaxf(ev.z + fmaf(bf2f(pv.z), dn, bp.z), 0.f);
            float x3 = fmaxf(ev.w + fmaf(bf2f(pv.w), dn, bp.w), 0.f);
            u0 = ((unsigned)f2bf(x1) << 16) | f2bf(x0);
            u1 = ((unsigned)f2bf(x3) << 16) | f2bf(x2);
        }
        *(uint2*)&xin_s[row * LW + q * 4] = make_uint2(u0, u1);
    }
    __syncthreads();
    int lane = t & 63, w = t >> 6;
    int l15 = lane & 15, l4 = lane >> 4;
    B128 bfr[4][2];
    #pragma unroll
    for (int nt = 0; nt < 4; nt++)
        #pragma unroll
        for (int ks = 0; ks < 2; ks++)
            bfr[nt][ks].u = *(const uint4*)&wt_s[(nt * 16 + l15) * LW + ks * 32 + l4 * 8];
    f32x4 acc[2][4] = {};
    #pragma unroll
    for (int m = 0; m < 2; m++) {
        int rb = w * 32 + m * 16;
        B128 a0, a1;
        a0.u = *(const uint4*)&xin_s[(rb + l15) * LW +  0 + l4 * 8];
        a1.u = *(const uint4*)&xin_s[(rb + l15) * LW + 32 + l4 * 8];
        #pragma unroll
        for (int nt = 0; nt < 4; nt++) {
            acc[m][nt] = __builtin_amdgcn_mfma_f32_16x16x32_bf16(a0.b, bfr[nt][0].b, acc[m][nt], 0, 0, 0);
            acc[m][nt] = __builtin_amdgcn_mfma_f32_16x16x32_bf16(a1.b, bfr[nt][1].b, acc[m][nt], 0, 0, 0);
        }
    }
    #pragma unroll
    for (int m = 0; m < 2; m++) {
        int Rbase = nb + w * 32 + m * 16;
        float dnr[4], d2r[4];
        #pragma unroll
        for (int r = 0; r < 4; r++) {
            int row = Rbase + l4 * 4 + r;
            bool v = row < N_NODES;
            dnr[r] = v ? dinv[row] : 0.f;
            d2r[r] = (POOLI && v) ? dinv2[row] : 0.f;
        }
        #pragma unroll
        for (int nt = 0; nt < 4; nt++)
            #pragma unroll
            for (int r = 0; r < 4; r++) {
                int row = Rbase + l4 * 4 + r;       // C layout: col=lane&15, row=(lane>>4)*4+reg [m89]
                if (row < N_NODES)
                    P[(size_t)row * 64 + nt * 16 + l15] = f2bf(acc[m][nt][r] * dnr[r]);
            }
        if (POOLI) {
            bool full = (Rbase + 15) < N_NODES;
            int g0 = -1, g15 = -2;
            if (full) { g0 = batch[Rbase]; g15 = batch[Rbase + 15]; }
            if (full && g0 == g15) {
                #pragma unroll
                for (int nt = 0; nt < 4; nt++) {
                    float v = 0.f;
                    #pragma unroll
                    for (int r = 0; r < 4; r++) v = fmaf(acc[m][nt][r], d2r[r], v);
                    v += __shfl_xor(v, 16);
                    v += __shfl_xor(v, 32);
                    if (lane < 16)
                        atomicAdd(&pool[g0 * 64 + nt * 16 + lane], fmaf(16.f, bcurr[nt * 16 + lane], v));
                }
            } else if (Rbase < N_NODES) {
                #pragma unroll
                for (int nt = 0; nt < 4; nt++) {
                    float bc = bcurr[nt * 16 + l15];
                    #pragma unroll
                    for (int r = 0; r < 4; r++) {
                        int row = Rbase + l4 * 4 + r;
                        if (row < N_NODES)
                            atomicAdd(&pool[batch[row] * 64 + nt * 16 + l15], fmaf(acc[m][nt][r], d2r[r], bc));
                    }
                }
            }
        }
    }
}

// ---------------- Edge-parallel aggregation (bf16 gather; interior-run plain stores) ----------------
// Wave owns 64 csr slots (node-sorted runs within one bucket).
// Out[dst] += dinv[dst] * sum(Pscaled[src])
// Runs not touching a window boundary are wave-exclusive -> plain coalesced 256B store;
// boundary runs use atomics (their E rows are pre-zeroed selectively by k_bcsr).
// POOLEP (layer 3): always atomic into pool[batch[dst]] (pool is shared, memset'd).
template<bool POOLEP>
__global__ __launch_bounds__(256, 8) void k_agge(const unsigned short* __restrict__ Hbuf,
                                                 const int* __restrict__ csr,
                                                 const int* __restrict__ bcur,
                                                 const float* __restrict__ dinv,
                                                 const int* __restrict__ batch,
                                                 float* __restrict__ Out) {
    int t = threadIdx.x;
    int wv   = t >> 6;
    int lane = t & 63;
    int wid  = blockIdx.x * 4 + wv;                // 0 .. SB*WPB-1
    int b    = wid / WPB;
    int lw   = wid - b * WPB;
    int used = bcur[b]; if (used > CAP) used = CAP;
    int e0   = lw * 64;
    int rem  = used - e0;
    if (rem <= 0) return;
    if (rem > 64) rem = 64;
    int base = b * CAP + e0;

    int p = 0;
    if (lane < rem) p = csr[base + lane];          // coalesced 256B (only load in init)
    int sv = p & 0x1FFFF;
    int dv = p >> 17;                              // dstLow (8b)

    // wave-uniform run-start mask (bit i: slot i starts a new dst run); bit 0 cleared
    int dvp = __shfl_up(dv, 1);
    unsigned long long m0 = __ballot(dv != dvp);
    unsigned mlo = __builtin_amdgcn_readfirstlane((unsigned)m0);
    unsigned mhi = __builtin_amdgcn_readfirstlane((unsigned)(m0 >> 32));
    unsigned long long mask = ((((unsigned long long)mhi) << 32) | mlo) & ~1ull;

    bool contL = (lw > 0);                         // run at slot 0 may continue left
    bool contR = (e0 + rem < used);                // run at slot rem-1 may continue right

    auto flush1 = [&](int dl, float a, bool atom) {
        int dst = (b << 8) + dl;
        if (dst < N_NODES) {
            float val = dinv[dst] * a;             // uniform load
            if (POOLEP) {
                int g = batch[dst];                // uniform load
                atomicAdd(&Out[g * 64 + lane], val);
            } else if (atom) {
                atomicAdd(&Out[(size_t)dst * 64 + lane], val);
            } else {
                Out[(size_t)dst * 64 + lane] = val; // exclusive run: plain store
            }
        }
    };

    int cur = rl_i(dv, 0);
    float acc = 0.f;
    bool first = true;                             // wave-uniform
    int j = 0;
    for (; j + 16 <= rem; j += 16) {
        unsigned short u[16];
        #pragma unroll
        for (int i = 0; i < 16; i++) {             // 16 gathers issued up front (r0 form)
            int s = rl_i(sv, j + i);
            u[i] = Hbuf[(size_t)s * 64 + lane];
        }
        #pragma unroll
        for (int i = 0; i < 16; i++) {
            if ((mask >> (j + i)) & 1) {           // scalar bit-test + scalar branch
                flush1(cur, acc, first && contL); first = false;
                acc = 0.f; cur = rl_i(dv, j + i);
            }
            acc += bf2f(u[i]);                     // 2 VALU/edge
        }
    }
    for (; j < rem; j++) {
        int s0 = rl_i(sv, j);
        unsigned short u0 = Hbuf[(size_t)s0 * 64 + lane];
        if ((mask >> j) & 1) {
            flush1(cur, acc, first && contL); first = false;
            acc = 0.f; cur = rl_i(dv, j);
        }
        acc += bf2f(u0);
    }
    flush1(cur, acc, (first && contL) || contR);
}

// ---------------- mean + classifier ----------------
__device__ __forceinline__ int lbound(const int* __restrict__ a, int n, int v) {
    int lo = 0, hi = n;
    while (lo < hi) { int m = (lo + hi) >> 1; if (a[m] < v) lo = m + 1; else hi = m; }
    return lo;
}

__global__ __launch_bounds__(64) void k_cls(const float* __restrict__ pool, const int* __restrict__ batch,
                                            const float* __restrict__ Wl, const float* __restrict__ bl,
                                            float* __restrict__ out) {
    __shared__ float pm[64];
    __shared__ int bounds[2];
    int g = blockIdx.x;
    int t = threadIdx.x;
    if (t < 2) bounds[t] = lbound(batch, N_NODES, g + t);
    __syncthreads();
    float cnt = (float)(bounds[1] - bounds[0]);
    pm[t] = pool[g * 64 + t] / fmaxf(cnt, 1.0f);
    __syncthreads();
    if (t < N_CLASSES) {
        float o = bl[t];
        #pragma unroll
        for (int k = 0; k < HID; k++) o = fmaf(pm[k], Wl[k * N_CLASSES + t], o);
        out[g * N_CLASSES + t] = o;
    }
}

// ---------------- launch ----------------

extern "C" void kernel_launch(void* const* d_in, const int* in_sizes, int n_in,
                              void* d_out, int out_size, void* d_ws, size_t ws_size,
                              hipStream_t stream) {
    const float* x     = (const float*)d_in[0];
    const int*   eidx  = (const int*)d_in[1];
    const int*   batch = (const int*)d_in[2];
    const float* W1 = (const float*)d_in[3];
    const float* b1 = (const float*)d_in[4];
    const float* W2 = (const float*)d_in[5];
    const float* b2 = (const float*)d_in[6];
    const float* W3 = (const float*)d_in[7];
    const float* b3 = (const float*)d_in[8];
    const float* Wl = (const float*)d_in[9];
    const float* bl = (const float*)d_in[10];
    const int* src = eidx;
    const int* dst = eidx + N_EDGES;

    char* p = (char*)d_ws;
    auto alloc = [&](size_t bytes) -> void* {
        void* r = (void*)p;
        p += (bytes + 255) & ~(size_t)255;
        return r;
    };
    float* dinv  = (float*)alloc((size_t)N_NODES * 4);
    float* dinv2 = (float*)alloc((size_t)N_NODES * 4);
    int*   csr   = (int*)  alloc((size_t)SB * CAP * 4);
    unsigned short* P = (unsigned short*)alloc((size_t)N_NODES * 64 * 2);  // bf16 H (scaled)
    float* E1    = (float*)alloc((size_t)N_NODES * 64 * 4);   // edge sums L1 (selective zero)
    float* pool  = (float*)alloc((size_t)N_GRAPHS * 64 * 4);
    float* E2    = (float*)alloc((size_t)N_NODES * 64 * 4);   // edge sums L2 (selective zero)
    int*   bcur  = (int*)  alloc((size_t)SB * 4);
    int*   binned = (int*) alloc((size_t)SB * CAP * 4);
    unsigned short* Wt = (unsigned short*)alloc((size_t)2 * 4096 * 2);  // bf16 W2^T, W3^T

    // ---- front: scatter | gemm1-MFMA (independent roles) ----
    hipMemsetAsync(bcur, 0, (size_t)SB * 4, stream);
    hipMemsetAsync(pool, 0, (size_t)N_GRAPHS * 64 * 4, stream);
    k_front<<<NCHUNK + GEMM_GRID, 256, 0, stream>>>(src, dst, bcur, binned, x, W1, P);
    // bcsr: degrees + LDS-staged csr + selective E zero + P scale | W2/W3 prep (2 blocks)
    k_bcsr <<<SB + 2, 1024, 0, stream>>>(binned, bcur, dinv, dinv2, csr, P, W2, W3, Wt, E1, E2);

    // layer 1 edges: scaled-H1 gathers -> E1
    k_agge<false><<<AGGE_GRID, 256, 0, stream>>>(P, csr, bcur, dinv, batch, E1);
    // layer 2: relu(E1 + b1 + Ps*dinv) @ W2 -> H2 (scaled, in-place in P); edges -> E2
    k_gemm<false><<<GEMM_GRID, 256, 0, stream>>>(E1, P, Wt, b1, nullptr, dinv, dinv2, batch, nullptr);
    k_agge<false><<<AGGE_GRID, 256, 0, stream>>>(P, csr, bcur, dinv, batch, E2);
    // layer 3: relu(E2 + b2 + Ps*dinv) @ W3 -> H3; self terms -> pool; edges -> pool
    k_gemm<true ><<<GEMM_GRID, 256, 0, stream>>>(E2, P, Wt + 4096, b2, b3, dinv, dinv2, batch, pool);
    k_agge<true ><<<AGGE_GRID, 256, 0, stream>>>(P, csr, bcur, dinv, batch, pool);

    // mean + classifier
    k_cls<<<N_GRAPHS, 64, 0, stream>>>(pool, batch, Wl, bl, (float*)d_out);
}